// Round 5
// baseline (228.519 us; speedup 1.0000x reference)
//
#include <hip/hip_runtime.h>

#define Bn 4
#define Ln 4096
#define Cn 128
#define DIn 256
#define NCn 128
#define LCn 32
#define ROWS (Bn*Ln)

typedef short s8v __attribute__((ext_vector_type(8)));
typedef short s4v __attribute__((ext_vector_type(4)));
typedef float f4v __attribute__((ext_vector_type(4)));

__device__ __forceinline__ float siluf(float x){ return x / (1.f + __expf(-x)); }
__device__ __forceinline__ float softplusf(float x){ return fmaxf(x,0.f) + __logf(1.f + __expf(-fabsf(x))); }

// split x into bf16 hi + bf16(residual): ~16-bit effective mantissa
__device__ __forceinline__ void splitbf(float x, short& h, short& l){
  uint u = __float_as_uint(x);
  uint hh = (u + 0x7fffu + ((u>>16)&1u)) >> 16;
  float hf = __uint_as_float(hh<<16);
  float r = x - hf;
  uint v = __float_as_uint(r);
  l = (short)((v + 0x7fffu + ((v>>16)&1u)) >> 16);
  h = (short)hh;
}

// LDS tile layout (per 128x32 operand tile, bf16): 8 subtiles of [16 rows][32 k],
// 512 shorts each. Granule XOR-swizzle keeps wave-wide s8v reads ~2-way (free, m136).
__device__ __forceinline__ int tile_off(int r, int gran, int ghalf){
  return ((r>>4)<<9) + ((r&15)<<5) + (((gran ^ ((r>>1)&3)))<<3) + ghalf;
}

// ---------------- G1 (MFMA split-bf16): xz[dir] = (dir? rev xs : xs) @ W_in[dir] ----------------
__global__ __launch_bounds__(256) void k_g1(const float* __restrict__ x,
    const float* __restrict__ Wf, const float* __restrict__ Wb,
    float* __restrict__ xzf, float* __restrict__ xzb)
{
  const int dir = blockIdx.z;
  const float* __restrict__ W = dir ? Wb : Wf;
  float* __restrict__ xz = dir ? xzb : xzf;
  const int row0 = blockIdx.x * 128;
  const int n0 = blockIdx.y * 128;
  const int b = row0 >> 12;
  const int t0 = row0 & (Ln-1);
  const float* __restrict__ xb = x + (size_t)b * Cn * Ln;

  __shared__ short Ah[8*512], Al[8*512], Bh[8*512], Bl[8*512];

  const int tid = threadIdx.x;
  const int lane = tid & 63;
  const int wid = tid >> 6;
  const int wr = wid >> 1, wc = wid & 1;
  const int r16 = lane & 15, kg = lane >> 4;

  const int q = tid & 31, kq = tid >> 5;
  const int kbase = 4*kq;
  const int g_true = kq >> 1;
  const int ghalf = (kq & 1) * 4;

  f4v acc[4][4];
  #pragma unroll
  for (int i=0;i<4;++i)
    #pragma unroll
    for (int j=0;j<4;++j) acc[i][j] = (f4v){0.f,0.f,0.f,0.f};

  for (int ks=0; ks<4; ++ks) {
    const int k0 = ks*32;
    if (ks) __syncthreads();
    {
      float4 va[4];
      if (dir==0) {
        #pragma unroll
        for (int kk=0;kk<4;++kk)
          va[kk] = *(const float4*)(xb + (size_t)(k0+kbase+kk)*Ln + t0 + 4*q);
      } else {
        #pragma unroll
        for (int kk=0;kk<4;++kk)
          va[kk] = *(const float4*)(xb + (size_t)(k0+kbase+kk)*Ln + (Ln-4 - t0 - 4*q));
      }
      #pragma unroll
      for (int e=0;e<4;++e) {
        int r = 4*q + e;
        int off = tile_off(r, g_true, ghalf);
        int c = dir ? (3-e) : e;
        s4v hv, lv;
        #pragma unroll
        for (int kk=0;kk<4;++kk) {
          float f = ((const float*)&va[kk])[c];
          short hh,ll; splitbf(f,hh,ll);
          hv[kk]=hh; lv[kk]=ll;
        }
        *(s4v*)&Ah[off] = hv;
        *(s4v*)&Al[off] = lv;
      }
    }
    {
      float4 vb[4];
      #pragma unroll
      for (int kk=0;kk<4;++kk)
        vb[kk] = *(const float4*)(W + (size_t)(k0+kbase+kk)*512 + n0 + 4*q);
      #pragma unroll
      for (int e=0;e<4;++e) {
        int r = 4*q + e;
        int off = tile_off(r, g_true, ghalf);
        s4v hv, lv;
        #pragma unroll
        for (int kk=0;kk<4;++kk) {
          float f = ((const float*)&vb[kk])[e];
          short hh,ll; splitbf(f,hh,ll);
          hv[kk]=hh; lv[kk]=ll;
        }
        *(s4v*)&Bh[off] = hv;
        *(s4v*)&Bl[off] = lv;
      }
    }
    __syncthreads();
    const int gsh = ((kg ^ ((r16>>1)&3)) << 3);
    s8v fah[4], fal[4], fbh[4], fbl[4];
    #pragma unroll
    for (int m=0;m<4;++m) {
      int idx = (wr*4+m)*512 + r16*32 + gsh;
      fah[m] = *(const s8v*)&Ah[idx];
      fal[m] = *(const s8v*)&Al[idx];
    }
    #pragma unroll
    for (int n=0;n<4;++n) {
      int idx = (wc*4+n)*512 + r16*32 + gsh;
      fbh[n] = *(const s8v*)&Bh[idx];
      fbl[n] = *(const s8v*)&Bl[idx];
    }
    #pragma unroll
    for (int m=0;m<4;++m)
      #pragma unroll
      for (int n=0;n<4;++n) {
        acc[m][n] = __builtin_amdgcn_mfma_f32_16x16x32_bf16(fah[m], fbh[n], acc[m][n], 0,0,0);
        acc[m][n] = __builtin_amdgcn_mfma_f32_16x16x32_bf16(fah[m], fbl[n], acc[m][n], 0,0,0);
        acc[m][n] = __builtin_amdgcn_mfma_f32_16x16x32_bf16(fal[m], fbh[n], acc[m][n], 0,0,0);
      }
  }
  #pragma unroll
  for (int m=0;m<4;++m)
    #pragma unroll
    for (int v=0;v<4;++v) {
      int row = row0 + wr*64 + m*16 + kg*4 + v;
      float* p = xz + (size_t)row*512 + n0 + wc*64 + r16;
      #pragma unroll
      for (int n=0;n<4;++n) p[n*16] = acc[m][n][v];
    }
}

// ---------------- conv ----------------
__global__ __launch_bounds__(256) void k_conv(
    const float* __restrict__ xzf, const float* __restrict__ xzb,
    const float* __restrict__ cwf, const float* __restrict__ cwb,
    const float* __restrict__ cbf, const float* __restrict__ cbb,
    float* __restrict__ xcf, float* __restrict__ xcb)
{
  const int dir = blockIdx.y;
  const float* __restrict__ xz = dir ? xzb : xzf;
  const float* __restrict__ cw = dir ? cwb : cwf;
  const float* __restrict__ cb = dir ? cbb : cbf;
  float* __restrict__ xc = dir ? xcb : xcf;
  const int n4 = ROWS * 64;
  for (int idx4 = blockIdx.x*256 + threadIdx.x; idx4 < n4; idx4 += gridDim.x*256) {
    int row = idx4 >> 6;
    int d0 = (idx4 & 63) * 4;
    float4 cur = *(const float4*)(xz + (size_t)row*512 + d0);
    float4 prev = make_float4(0.f,0.f,0.f,0.f);
    if (row & (Ln-1)) prev = *(const float4*)(xz + (size_t)(row-1)*512 + d0);
    float4 cwA = *(const float4*)(cw + d0*2);
    float4 cwB = *(const float4*)(cw + d0*2 + 4);
    float4 cb4 = *(const float4*)(cb + d0);
    float4 r;
    r.x = siluf(fmaf(prev.x,cwA.x, fmaf(cur.x,cwA.y, cb4.x)));
    r.y = siluf(fmaf(prev.y,cwA.z, fmaf(cur.y,cwA.w, cb4.y)));
    r.z = siluf(fmaf(prev.z,cwB.x, fmaf(cur.z,cwB.y, cb4.z)));
    r.w = siluf(fmaf(prev.w,cwB.z, fmaf(cur.w,cwB.w, cb4.w)));
    *(float4*)(xc + (size_t)row*256 + d0) = r;
  }
}

// ---------------- G2: xdb = xc @ W_x ----------------
__global__ __launch_bounds__(256) void k_g2(
    const float* __restrict__ xcf, const float* __restrict__ xcb,
    const float* __restrict__ Wxf, const float* __restrict__ Wxb,
    float* __restrict__ xdbf, float* __restrict__ xdbb)
{
  const int dir = blockIdx.z;
  const float* __restrict__ xc = dir ? xcb : xcf;
  const float* __restrict__ Wx = dir ? Wxb : Wxf;
  float* __restrict__ xdb = dir ? xdbb : xdbf;
  const int row0 = blockIdx.x * 128;
  __shared__ float As[16][132];
  __shared__ float Bs[16][64];
  const int tid = threadIdx.x;
  const int tx = tid & 15, ty = tid >> 4;
  float acc[8][4];
  #pragma unroll
  for (int i=0;i<8;++i)
    #pragma unroll
    for (int j=0;j<4;++j) acc[i][j]=0.f;

  for (int k0 = 0; k0 < 256; k0 += 16) {
    #pragma unroll
    for (int j = 0; j < 2; ++j) {
      int f = tid + j*256;
      int r = f >> 2, v = f & 3;
      float4 t4 = *(const float4*)(xc + (size_t)(row0+r)*256 + k0 + v*4);
      As[v*4+0][r]=t4.x; As[v*4+1][r]=t4.y; As[v*4+2][r]=t4.z; As[v*4+3][r]=t4.w;
    }
    #pragma unroll
    for (int j = 0; j < 4; ++j) {
      int idx = tid + j*256;
      int k = idx >> 6, n = idx & 63;
      Bs[k][n] = (n < 40) ? Wx[(size_t)(k0+k)*40 + n] : 0.f;
    }
    __syncthreads();
    #pragma unroll
    for (int kk=0;kk<16;++kk) {
      float a[8], bv[4];
      *(float4*)&a[0] = *(const float4*)&As[kk][ty*8];
      *(float4*)&a[4] = *(const float4*)&As[kk][ty*8+4];
      *(float4*)&bv[0] = *(const float4*)&Bs[kk][tx*4];
      #pragma unroll
      for (int i=0;i<8;++i)
        #pragma unroll
        for (int j=0;j<4;++j) acc[i][j] = fmaf(a[i], bv[j], acc[i][j]);
    }
    __syncthreads();
  }
  if (tx < 10) {
    #pragma unroll
    for (int i=0;i<8;++i)
      #pragma unroll
      for (int j=0;j<4;++j)
        xdb[(size_t)(row0+ty*8+i)*40 + tx*4 + j] = acc[i][j];
  }
}

// ---------------- pass1: per-chunk local scan (LCn=32) ----------------
__global__ __launch_bounds__(256,4) void k_pass1(
    const float* __restrict__ xdbf, const float* __restrict__ xdbb,
    const float* __restrict__ xcf, const float* __restrict__ xcb,
    const float* __restrict__ Wdtf, const float* __restrict__ Wdtb,
    const float* __restrict__ bdtf, const float* __restrict__ bdtb,
    const float* __restrict__ Alf, const float* __restrict__ Alb,
    float* __restrict__ sdtf, float* __restrict__ sdtb,
    float* __restrict__ hkf, float* __restrict__ hkb)
{
  const int dir = blockIdx.y;
  const float* __restrict__ xdb = dir ? xdbb : xdbf;
  const float* __restrict__ xc  = dir ? xcb  : xcf;
  const float* __restrict__ Wdt = dir ? Wdtb : Wdtf;
  const float* __restrict__ bdt = dir ? bdtb : bdtf;
  const float* __restrict__ Al  = dir ? Alb  : Alf;
  float* __restrict__ sdt = dir ? sdtb : sdtf;
  float* __restrict__ hk  = dir ? hkb  : hkf;
  const int b = blockIdx.x >> 7, c = blockIdx.x & 127;
  const int t0 = c * LCn;
  __shared__ float S[LCn][24];
  const int tid = threadIdx.x;
  #pragma unroll
  for (int j=0;j<3;++j) {
    int idx = tid + j*256;
    int t = idx/24, jj = idx - t*24;
    S[t][jj] = xdb[(size_t)(b*Ln + t0 + t)*40 + jj];
  }
  const int d = tid;
  float Areg[16];
  #pragma unroll
  for (int s=0;s<16;++s) Areg[s] = -__expf(Al[d*16+s]);
  float wdt[8];
  #pragma unroll
  for (int j=0;j<8;++j) wdt[j] = Wdt[j*256+d];
  const float bd = bdt[d];
  float h[16];
  #pragma unroll
  for (int s=0;s<16;++s) h[s]=0.f;
  float sacc = 0.f;
  __syncthreads();
  #pragma unroll 2
  for (int t=0;t<LCn;++t) {
    float dtv = bd;
    #pragma unroll
    for (int j=0;j<8;++j) dtv = fmaf(S[t][j], wdt[j], dtv);
    dtv = softplusf(dtv);
    float xv = xc[(size_t)(b*Ln + t0 + t)*256 + d];
    float u = dtv * xv;
    sacc += dtv;
    #pragma unroll
    for (int s=0;s<16;++s)
      h[s] = fmaf(__expf(dtv*Areg[s]), h[s], u*S[t][8+s]);
  }
  sdt[(size_t)(b*NCn + c)*256 + d] = sacc;
  #pragma unroll
  for (int s=0;s<16;++s)
    hk[(size_t)((b*NCn + c)*16 + s)*256 + d] = h[s];
}

// ---------------- pass2: inter-chunk recurrence (chain = NCn) ----------------
__global__ __launch_bounds__(256) void k_pass2(
    const float* __restrict__ Alf, const float* __restrict__ Alb,
    const float* __restrict__ sdtf, const float* __restrict__ sdtb,
    float* __restrict__ hkf, float* __restrict__ hkb)
{
  const int dir = blockIdx.y;
  const float* __restrict__ Al  = dir ? Alb : Alf;
  const float* __restrict__ sdt = dir ? sdtb : sdtf;
  float* __restrict__ hk = dir ? hkb : hkf;
  int g = blockIdx.x*256 + threadIdx.x;
  int d = g & 255, s = (g >> 8) & 15, b = g >> 12;
  float Ad = -__expf(Al[d*16+s]);
  float h = 0.f;
  #pragma unroll 2
  for (int c=0;c<NCn;++c) {
    int bc = b*NCn + c;
    float sd = sdt[(size_t)bc*256 + d];
    size_t hi = (size_t)(bc*16 + s)*256 + d;
    float he = hk[hi];
    hk[hi] = h;
    h = fmaf(__expf(Ad*sd), h, he);
  }
}

// ---------------- pass3: replay chunk; y + D*xc, gate silu(z) ----------------
__global__ __launch_bounds__(256,4) void k_pass3(
    const float* __restrict__ xdbf, const float* __restrict__ xdbb,
    const float* __restrict__ xcf, const float* __restrict__ xcb,
    const float* __restrict__ Wdtf, const float* __restrict__ Wdtb,
    const float* __restrict__ bdtf, const float* __restrict__ bdtb,
    const float* __restrict__ Alf, const float* __restrict__ Alb,
    const float* __restrict__ Dvf, const float* __restrict__ Dvb,
    const float* __restrict__ hkf, const float* __restrict__ hkb,
    float* __restrict__ xzf, float* __restrict__ xzb)
{
  const int dir = blockIdx.y;
  const float* __restrict__ xdb = dir ? xdbb : xdbf;
  const float* __restrict__ xc  = dir ? xcb  : xcf;
  const float* __restrict__ Wdt = dir ? Wdtb : Wdtf;
  const float* __restrict__ bdt = dir ? bdtb : bdtf;
  const float* __restrict__ Al  = dir ? Alb  : Alf;
  const float* __restrict__ Dv  = dir ? Dvb  : Dvf;
  const float* __restrict__ hk  = dir ? hkb  : hkf;
  float* __restrict__ xz = dir ? xzb : xzf;
  const int b = blockIdx.x >> 7, c = blockIdx.x & 127;
  const int t0 = c * LCn;
  __shared__ float S[LCn][40];
  const int tid = threadIdx.x;
  #pragma unroll
  for (int j=0;j<5;++j) {
    int idx = tid + j*256;
    int t = idx/40, jj = idx - t*40;
    S[t][jj] = xdb[(size_t)(b*Ln + t0 + t)*40 + jj];
  }
  const int d = tid;
  float Areg[16];
  #pragma unroll
  for (int s=0;s<16;++s) Areg[s] = -__expf(Al[d*16+s]);
  float wdt[8];
  #pragma unroll
  for (int j=0;j<8;++j) wdt[j] = Wdt[j*256+d];
  const float bd = bdt[d];
  const float Dd = Dv[d];
  float h[16];
  #pragma unroll
  for (int s=0;s<16;++s) h[s] = hk[(size_t)((b*NCn + c)*16 + s)*256 + d];
  __syncthreads();
  #pragma unroll 2
  for (int t=0;t<LCn;++t) {
    float dtv = bd;
    #pragma unroll
    for (int j=0;j<8;++j) dtv = fmaf(S[t][j], wdt[j], dtv);
    dtv = softplusf(dtv);
    size_t rowi = (size_t)(b*Ln + t0 + t);
    float xv = xc[rowi*256 + d];
    float u = dtv * xv;
    float y = 0.f;
    #pragma unroll
    for (int s=0;s<16;++s) {
      h[s] = fmaf(__expf(dtv*Areg[s]), h[s], u*S[t][8+s]);
      y = fmaf(h[s], S[t][24+s], y);
    }
    y = fmaf(Dd, xv, y);
    float zv = xz[rowi*512 + 256 + d];
    xz[rowi*512 + 256 + d] = y * siluf(zv);
  }
}

// ---------------- Gout (MFMA split-bf16) ----------------
__global__ __launch_bounds__(256) void k_gout(
    const float* __restrict__ xzf, const float* __restrict__ xzb,
    const float* __restrict__ Wof, const float* __restrict__ Wob,
    float* __restrict__ ysum)
{
  const int row0 = blockIdx.x * 128;
  const int b = row0 >> 12;
  const int l0 = row0 & (Ln-1);

  __shared__ short Ah[8*512], Al[8*512], Bh[8*512], Bl[8*512];

  const int tid = threadIdx.x;
  const int lane = tid & 63;
  const int wid = tid >> 6;
  const int wr = wid >> 1, wc = wid & 1;
  const int r16 = lane & 15, kg = lane >> 4;

  const int ar = tid >> 1;
  const int kseg = (tid & 1) * 16;
  const int arl = ar & 15, amt = ar >> 4;
  const int asw = (arl >> 1) & 3;
  const int q = tid & 31, kq = tid >> 5;
  const int kbase = 4*kq;
  const int g_true = kq >> 1;
  const int ghalf = (kq & 1) * 4;

  f4v acc[4][4];
  #pragma unroll
  for (int i=0;i<4;++i)
    #pragma unroll
    for (int j=0;j<4;++j) acc[i][j] = (f4v){0.f,0.f,0.f,0.f};

  for (int ks=0; ks<16; ++ks) {
    const int dir = ks >> 3;
    const int kk0 = (ks & 7) * 32;
    const float* __restrict__ xzd = dir ? xzb : xzf;
    const float* __restrict__ Wod = dir ? Wob : Wof;
    if (ks) __syncthreads();
    {
      int rl = l0 + ar;
      size_t srow = (size_t)b*Ln + (dir ? (Ln-1-rl) : rl);
      const float* s = xzd + srow*512 + 256 + kk0 + kseg;
      short* ph = &Ah[amt*512 + arl*32];
      short* pl = &Al[amt*512 + arl*32];
      #pragma unroll
      for (int i=0;i<4;++i) {
        float4 v = *(const float4*)(s + 4*i);
        float vv[4] = {v.x,v.y,v.z,v.w};
        s4v hq, lq;
        #pragma unroll
        for (int e=0;e<4;++e) { short hh,ll; splitbf(vv[e],hh,ll); hq[e]=hh; lq[e]=ll; }
        int kl = kseg + 4*i;
        int off = (((kl>>3)^asw)<<3) + (kl&7);
        *(s4v*)(ph + off) = hq;
        *(s4v*)(pl + off) = lq;
      }
    }
    {
      float4 vb[4];
      #pragma unroll
      for (int kk=0;kk<4;++kk)
        vb[kk] = *(const float4*)(Wod + (size_t)(kk0+kbase+kk)*128 + 4*q);
      #pragma unroll
      for (int e=0;e<4;++e) {
        int r = 4*q + e;
        int off = tile_off(r, g_true, ghalf);
        s4v hv, lv;
        #pragma unroll
        for (int kk=0;kk<4;++kk) {
          float f = ((const float*)&vb[kk])[e];
          short hh,ll; splitbf(f,hh,ll);
          hv[kk]=hh; lv[kk]=ll;
        }
        *(s4v*)&Bh[off] = hv;
        *(s4v*)&Bl[off] = lv;
      }
    }
    __syncthreads();
    const int gsh = ((kg ^ ((r16>>1)&3)) << 3);
    s8v fah[4], fal[4], fbh[4], fbl[4];
    #pragma unroll
    for (int m=0;m<4;++m) {
      int idx = (wr*4+m)*512 + r16*32 + gsh;
      fah[m] = *(const s8v*)&Ah[idx];
      fal[m] = *(const s8v*)&Al[idx];
    }
    #pragma unroll
    for (int n=0;n<4;++n) {
      int idx = (wc*4+n)*512 + r16*32 + gsh;
      fbh[n] = *(const s8v*)&Bh[idx];
      fbl[n] = *(const s8v*)&Bl[idx];
    }
    #pragma unroll
    for (int m=0;m<4;++m)
      #pragma unroll
      for (int n=0;n<4;++n) {
        acc[m][n] = __builtin_amdgcn_mfma_f32_16x16x32_bf16(fah[m], fbh[n], acc[m][n], 0,0,0);
        acc[m][n] = __builtin_amdgcn_mfma_f32_16x16x32_bf16(fah[m], fbl[n], acc[m][n], 0,0,0);
        acc[m][n] = __builtin_amdgcn_mfma_f32_16x16x32_bf16(fal[m], fbh[n], acc[m][n], 0,0,0);
      }
  }
  #pragma unroll
  for (int m=0;m<4;++m)
    #pragma unroll
    for (int v=0;v<4;++v) {
      int row = row0 + wr*64 + m*16 + kg*4 + v;
      float* p = ysum + (size_t)row*128 + wc*64 + r16;
      #pragma unroll
      for (int n=0;n<4;++n) p[n*16] = acc[m][n][v];
    }
}

// ---------------- GroupNorm stats (partials) ----------------
__global__ __launch_bounds__(256) void k_gnstat(const float* __restrict__ ysum, float* __restrict__ part)
{
  const int bg = blockIdx.x >> 4;
  const int blk = blockIdx.x & 15;
  const int b = bg >> 2, g = bg & 3;
  float s=0.f, q=0.f;
  #pragma unroll
  for (int i=0;i<8;++i) {
    int e4 = blk*2048 + threadIdx.x + i*256;
    int l = e4 >> 3, c4 = e4 & 7;
    float4 v = *(const float4*)(ysum + (size_t)(b*Ln + l)*128 + g*32 + c4*4);
    s += v.x+v.y+v.z+v.w;
    q = fmaf(v.x,v.x, fmaf(v.y,v.y, fmaf(v.z,v.z, fmaf(v.w,v.w, q))));
  }
  __shared__ float rs[256], rq[256];
  rs[threadIdx.x]=s; rq[threadIdx.x]=q;
  __syncthreads();
  for (int off=128; off>0; off>>=1) {
    if (threadIdx.x < off) { rs[threadIdx.x]+=rs[threadIdx.x+off]; rq[threadIdx.x]+=rq[threadIdx.x+off]; }
    __syncthreads();
  }
  if (threadIdx.x==0) { part[blockIdx.x*2]=rs[0]; part[blockIdx.x*2+1]=rq[0]; }
}

__global__ void k_gnred(const float* __restrict__ part, float* __restrict__ mr)
{
  int t = threadIdx.x;
  if (t < 16) {
    float s=0.f,q=0.f;
    for (int k=0;k<16;++k){ s+=part[(t*16+k)*2]; q+=part[(t*16+k)*2+1]; }
    const float inv = 1.f/131072.f;
    float mean = s*inv;
    float var = fmaf(-mean, mean, q*inv);
    mr[t*2] = mean;
    mr[t*2+1] = rsqrtf(var + 1e-5f);
  }
}

// ---------------- GN apply + silu + residual ----------------
__global__ __launch_bounds__(256) void k_gnapply(const float* __restrict__ ysum,
    const float* __restrict__ mr, const float* __restrict__ gamma, const float* __restrict__ beta,
    const float* __restrict__ x, float* __restrict__ out)
{
  const int b = blockIdx.x >> 6;
  const int l0 = (blockIdx.x & 63) * 64;
  __shared__ float T[64][132];
  const int tid = threadIdx.x;
  #pragma unroll
  for (int j=0;j<8;++j) {
    int f = tid + j*256;
    int l = f >> 5, c4 = f & 31;
    *(float4*)&T[l][c4*4] = *(const float4*)(ysum + (size_t)(b*Ln + l0 + l)*128 + c4*4);
  }
  __syncthreads();
  #pragma unroll
  for (int j=0;j<8;++j) {
    int f = tid + j*256;
    int c = f >> 4, lv = f & 15;
    int bg = b*4 + (c>>5);
    float mean = mr[bg*2];
    float rstd = mr[bg*2+1];
    float gam = gamma[c], bet = beta[c];
    size_t base = (size_t)(b*Cn + c)*Ln + l0 + lv*4;
    float4 xv = *(const float4*)(x + base);
    float4 r;
    r.x = siluf(fmaf((T[lv*4+0][c]-mean)*rstd, gam, bet)) + xv.x;
    r.y = siluf(fmaf((T[lv*4+1][c]-mean)*rstd, gam, bet)) + xv.y;
    r.z = siluf(fmaf((T[lv*4+2][c]-mean)*rstd, gam, bet)) + xv.z;
    r.w = siluf(fmaf((T[lv*4+3][c]-mean)*rstd, gam, bet)) + xv.w;
    *(float4*)(out + base) = r;
  }
}

extern "C" void kernel_launch(void* const* d_in, const int* in_sizes, int n_in,
                              void* d_out, int out_size, void* d_ws, size_t ws_size,
                              hipStream_t stream) {
  const float* x      = (const float*)d_in[0];
  const float* W_in_f = (const float*)d_in[1];
  const float* cw_f   = (const float*)d_in[2];
  const float* cb_f   = (const float*)d_in[3];
  const float* Wx_f   = (const float*)d_in[4];
  const float* Wdt_f  = (const float*)d_in[5];
  const float* bdt_f  = (const float*)d_in[6];
  const float* Al_f   = (const float*)d_in[7];
  const float* D_f    = (const float*)d_in[8];
  const float* Wo_f   = (const float*)d_in[9];
  const float* W_in_b = (const float*)d_in[10];
  const float* cw_b   = (const float*)d_in[11];
  const float* cb_b   = (const float*)d_in[12];
  const float* Wx_b   = (const float*)d_in[13];
  const float* Wdt_b  = (const float*)d_in[14];
  const float* bdt_b  = (const float*)d_in[15];
  const float* Al_b   = (const float*)d_in[16];
  const float* D_b    = (const float*)d_in[17];
  const float* Wo_b   = (const float*)d_in[18];
  const float* gamma  = (const float*)d_in[19];
  const float* beta   = (const float*)d_in[20];
  float* out = (float*)d_out;

  float* w = (float*)d_ws;
  size_t o = 0;
  float* xz0  = w + o; o += (size_t)ROWS*512;
  float* xz1  = w + o; o += (size_t)ROWS*512;
  float* xc0  = w + o; o += (size_t)ROWS*256;
  float* xc1  = w + o; o += (size_t)ROWS*256;
  // dead-after-pass3 block: xdb0 xdb1 sdt0 sdt1 hk0 hk1 — ysum aliases its start
  float* xdb0 = w + o; o += (size_t)ROWS*40;
  float* xdb1 = w + o; o += (size_t)ROWS*40;
  float* sdt0 = w + o; o += (size_t)Bn*NCn*256;
  float* sdt1 = w + o; o += (size_t)Bn*NCn*256;
  float* hk0  = w + o; o += (size_t)Bn*NCn*16*256;
  float* hk1  = w + o; o += (size_t)Bn*NCn*16*256;
  float* ysum = xdb0;  // ROWS*128 = 2,097,152 floats <= dead block (5,767,168)
  float* part = w + o; o += 512;
  float* mr   = w + o; o += 32;
  if (ws_size < o*sizeof(float)) return;

  k_g1<<<dim3(ROWS/128, 4, 2), 256, 0, stream>>>(x, W_in_f, W_in_b, xz0, xz1);
  k_conv<<<dim3(1024, 2), 256, 0, stream>>>(xz0, xz1, cw_f, cw_b, cb_f, cb_b, xc0, xc1);
  k_g2<<<dim3(ROWS/128, 1, 2), 256, 0, stream>>>(xc0, xc1, Wx_f, Wx_b, xdb0, xdb1);
  k_pass1<<<dim3(Bn*NCn, 2), 256, 0, stream>>>(xdb0, xdb1, xc0, xc1, Wdt_f, Wdt_b,
                                               bdt_f, bdt_b, Al_f, Al_b, sdt0, sdt1, hk0, hk1);
  k_pass2<<<dim3(64, 2), 256, 0, stream>>>(Al_f, Al_b, sdt0, sdt1, hk0, hk1);
  k_pass3<<<dim3(Bn*NCn, 2), 256, 0, stream>>>(xdb0, xdb1, xc0, xc1, Wdt_f, Wdt_b,
                                               bdt_f, bdt_b, Al_f, Al_b, D_f, D_b,
                                               hk0, hk1, xz0, xz1);
  k_gout<<<dim3(ROWS/128), 256, 0, stream>>>(xz0, xz1, Wo_f, Wo_b, ysum);
  k_gnstat<<<dim3(256), 256, 0, stream>>>(ysum, part);
  k_gnred<<<dim3(1), 64, 0, stream>>>(part, mr);
  k_gnapply<<<dim3(256), 256, 0, stream>>>(ysum, mr, gamma, beta, x, out);
}

// Round 6
// 199.598 us; speedup vs baseline: 1.1449x; 1.1449x over previous
//
#include <hip/hip_runtime.h>

#define Bn 4
#define Ln 4096
#define Cn 128
#define DIn 256
#define NCn 128
#define LCn 32
#define ROWS (Bn*Ln)

typedef short s8v __attribute__((ext_vector_type(8)));
typedef short s4v __attribute__((ext_vector_type(4)));
typedef unsigned short u8v __attribute__((ext_vector_type(8)));
typedef unsigned short u4v __attribute__((ext_vector_type(4)));
typedef float f4v __attribute__((ext_vector_type(4)));

__device__ __forceinline__ float siluf(float x){ return x / (1.f + __expf(-x)); }
__device__ __forceinline__ float softplusf(float x){ return fmaxf(x,0.f) + __logf(1.f + __expf(-fabsf(x))); }
__device__ __forceinline__ unsigned short bfr(float f){
  uint u = __float_as_uint(f);
  return (unsigned short)((u + 0x7fffu + ((u>>16)&1u)) >> 16);
}
__device__ __forceinline__ float bf2f(unsigned short u){ return __uint_as_float(((uint)u)<<16); }

// LDS tile layout (128x32 bf16 tile): 8 subtiles [16r][32k]; granule (8 shorts)
// XOR-swizzled by ((r>>1)&3) -> wave s8v reads are ~2-way bank-aliased (free, m136).
__device__ __forceinline__ int tile_off(int r, int gran, int ghalf){
  return ((r>>4)<<9) + ((r&15)<<5) + (((gran ^ ((r>>1)&3)))<<3) + ghalf;
}

#define SMEMB 18432

// ---------------- G1 (bf16 MFMA): xz = (dir? rev xs : xs) @ W_in ----------------
// outputs: xp[dir] f32 (cols 0..255), zb[dir] bf16 (cols 256..511)
__global__ __launch_bounds__(256) void k_g1(const float* __restrict__ x,
    const float* __restrict__ Wf, const float* __restrict__ Wb,
    float* __restrict__ xpf, float* __restrict__ xpb,
    unsigned short* __restrict__ zbf, unsigned short* __restrict__ zbb)
{
  const int dir = blockIdx.z;
  const float* __restrict__ W = dir ? Wb : Wf;
  float* __restrict__ xp = dir ? xpb : xpf;
  unsigned short* __restrict__ zb = dir ? zbb : zbf;
  const int row0 = blockIdx.x * 128;
  const int n0 = blockIdx.y;                  // 0..3 (x: 0,1  z: 2,3)
  const int b = row0 >> 12;
  const int t0 = row0 & (Ln-1);
  const float* __restrict__ xb = x + (size_t)b * Cn * Ln;

  __shared__ __align__(16) char smem[SMEMB];
  short* Ast = (short*)smem;
  short* Bst = (short*)smem + 8*512;
  float* Te  = (float*)smem;

  const int tid = threadIdx.x;
  const int lane = tid & 63;
  const int wid = tid >> 6;
  const int wr = wid >> 1, wc = wid & 1;
  const int r16 = lane & 15, kg = lane >> 4;

  const int q = tid & 31, kq = tid >> 5;
  const int kbase = 4*kq;
  const int g_true = kq >> 1;
  const int ghalf = (kq & 1) * 4;

  f4v acc[4][4];
  #pragma unroll
  for (int i=0;i<4;++i)
    #pragma unroll
    for (int j=0;j<4;++j) acc[i][j] = (f4v){0.f,0.f,0.f,0.f};

  float4 va[4], vb[4];
  // prologue loads (ks=0)
  {
    #pragma unroll
    for (int kk=0;kk<4;++kk) {
      va[kk] = (dir==0)
        ? *(const float4*)(xb + (size_t)(kbase+kk)*Ln + t0 + 4*q)
        : *(const float4*)(xb + (size_t)(kbase+kk)*Ln + (Ln-4 - t0 - 4*q));
      vb[kk] = *(const float4*)(W + (size_t)(kbase+kk)*512 + n0*128 + 4*q);
    }
  }
  for (int ks=0; ks<4; ++ks) {
    if (ks) __syncthreads();
    // stage from regs
    #pragma unroll
    for (int e=0;e<4;++e) {
      int r = 4*q + e;
      int off = tile_off(r, g_true, ghalf);
      int c = dir ? (3-e) : e;
      s4v hv;
      #pragma unroll
      for (int kk=0;kk<4;++kk) hv[kk] = (short)bfr(((const float*)&va[kk])[c]);
      *(s4v*)&Ast[off] = hv;
    }
    #pragma unroll
    for (int e=0;e<4;++e) {
      int r = 4*q + e;
      int off = tile_off(r, g_true, ghalf);
      s4v hv;
      #pragma unroll
      for (int kk=0;kk<4;++kk) hv[kk] = (short)bfr(((const float*)&vb[kk])[e]);
      *(s4v*)&Bst[off] = hv;
    }
    __syncthreads();
    if (ks < 3) {
      const int k0n = (ks+1)*32;
      #pragma unroll
      for (int kk=0;kk<4;++kk) {
        va[kk] = (dir==0)
          ? *(const float4*)(xb + (size_t)(k0n+kbase+kk)*Ln + t0 + 4*q)
          : *(const float4*)(xb + (size_t)(k0n+kbase+kk)*Ln + (Ln-4 - t0 - 4*q));
        vb[kk] = *(const float4*)(W + (size_t)(k0n+kbase+kk)*512 + n0*128 + 4*q);
      }
    }
    const int gsh = ((kg ^ ((r16>>1)&3)) << 3);
    s8v fa[4], fb[4];
    #pragma unroll
    for (int m=0;m<4;++m) fa[m] = *(const s8v*)&Ast[(wr*4+m)*512 + r16*32 + gsh];
    #pragma unroll
    for (int n=0;n<4;++n) fb[n] = *(const s8v*)&Bst[(wc*4+n)*512 + r16*32 + gsh];
    #pragma unroll
    for (int m=0;m<4;++m)
      #pragma unroll
      for (int n=0;n<4;++n)
        acc[m][n] = __builtin_amdgcn_mfma_f32_16x16x32_bf16(fa[m], fb[n], acc[m][n], 0,0,0);
  }
  // ---- epilogue: per-wave LDS transpose -> coalesced stores
  __syncthreads();
  float* Tw = Te + wid*1088;             // 16x68 f32 region per wave
  #pragma unroll
  for (int m=0;m<4;++m) {
    #pragma unroll
    for (int n=0;n<4;++n)
      #pragma unroll
      for (int v=0;v<4;++v)
        Tw[(kg*4+v)*68 + n*16 + r16] = acc[m][n][v];
    #pragma unroll
    for (int rr=0;rr<4;++rr) {
      int r = rr*4 + (lane>>4);
      int c4 = lane & 15;
      float4 v4 = *(const float4*)&Tw[r*68 + c4*4];
      int row = row0 + wr*64 + m*16 + r;
      int colL = wc*64 + c4*4;
      if (n0 < 2) {
        *(float4*)(xp + (size_t)row*256 + n0*128 + colL) = v4;
      } else {
        u4v u; u[0]=bfr(v4.x); u[1]=bfr(v4.y); u[2]=bfr(v4.z); u[3]=bfr(v4.w);
        *(u4v*)(zb + (size_t)row*256 + (n0-2)*128 + colL) = u;
      }
    }
  }
}

// ---------------- conv: xc = silu(xp[t-1]*w0 + xp[t]*w1 + cb) -> bf16 ----------------
__global__ __launch_bounds__(256) void k_conv(
    const float* __restrict__ xpf, const float* __restrict__ xpb,
    const float* __restrict__ cwf, const float* __restrict__ cwb,
    const float* __restrict__ cbf, const float* __restrict__ cbb,
    unsigned short* __restrict__ xcf, unsigned short* __restrict__ xcb)
{
  const int dir = blockIdx.y;
  const float* __restrict__ xpd = dir ? xpb : xpf;
  const float* __restrict__ cw = dir ? cwb : cwf;
  const float* __restrict__ cb = dir ? cbb : cbf;
  unsigned short* __restrict__ xc = dir ? xcb : xcf;
  const int n4 = ROWS * 64;
  for (int idx4 = blockIdx.x*256 + threadIdx.x; idx4 < n4; idx4 += gridDim.x*256) {
    int row = idx4 >> 6;
    int d0 = (idx4 & 63) * 4;
    float4 cur = *(const float4*)(xpd + (size_t)row*256 + d0);
    float4 prev = make_float4(0.f,0.f,0.f,0.f);
    if (row & (Ln-1)) prev = *(const float4*)(xpd + (size_t)(row-1)*256 + d0);
    float4 cwA = *(const float4*)(cw + d0*2);
    float4 cwB = *(const float4*)(cw + d0*2 + 4);
    float4 cb4 = *(const float4*)(cb + d0);
    u4v r;
    r[0] = bfr(siluf(fmaf(prev.x,cwA.x, fmaf(cur.x,cwA.y, cb4.x))));
    r[1] = bfr(siluf(fmaf(prev.y,cwA.z, fmaf(cur.y,cwA.w, cb4.y))));
    r[2] = bfr(siluf(fmaf(prev.z,cwB.x, fmaf(cur.z,cwB.y, cb4.z))));
    r[3] = bfr(siluf(fmaf(prev.w,cwB.z, fmaf(cur.w,cwB.w, cb4.w))));
    *(u4v*)(xc + (size_t)row*256 + d0) = r;
  }
}

// ---------------- G2: xdb = xc @ W_x  (bf16 A source) ----------------
__global__ __launch_bounds__(256) void k_g2(
    const unsigned short* __restrict__ xcf, const unsigned short* __restrict__ xcb,
    const float* __restrict__ Wxf, const float* __restrict__ Wxb,
    float* __restrict__ xdbf, float* __restrict__ xdbb)
{
  const int dir = blockIdx.z;
  const unsigned short* __restrict__ xc = dir ? xcb : xcf;
  const float* __restrict__ Wx = dir ? Wxb : Wxf;
  float* __restrict__ xdb = dir ? xdbb : xdbf;
  const int row0 = blockIdx.x * 128;
  __shared__ float As[16][132];
  __shared__ float Bs[16][64];
  const int tid = threadIdx.x;
  const int tx = tid & 15, ty = tid >> 4;
  float acc[8][4];
  #pragma unroll
  for (int i=0;i<8;++i)
    #pragma unroll
    for (int j=0;j<4;++j) acc[i][j]=0.f;

  for (int k0 = 0; k0 < 256; k0 += 16) {
    {
      int r = tid >> 1, half = tid & 1;
      u8v u = *(const u8v*)(xc + (size_t)(row0+r)*256 + k0 + half*8);
      #pragma unroll
      for (int i=0;i<8;++i) As[half*8+i][r] = bf2f(u[i]);
    }
    #pragma unroll
    for (int j = 0; j < 4; ++j) {
      int idx = tid + j*256;
      int k = idx >> 6, n = idx & 63;
      Bs[k][n] = (n < 40) ? Wx[(size_t)(k0+k)*40 + n] : 0.f;
    }
    __syncthreads();
    #pragma unroll
    for (int kk=0;kk<16;++kk) {
      float a[8], bv[4];
      *(float4*)&a[0] = *(const float4*)&As[kk][ty*8];
      *(float4*)&a[4] = *(const float4*)&As[kk][ty*8+4];
      *(float4*)&bv[0] = *(const float4*)&Bs[kk][tx*4];
      #pragma unroll
      for (int i=0;i<8;++i)
        #pragma unroll
        for (int j=0;j<4;++j) acc[i][j] = fmaf(a[i], bv[j], acc[i][j]);
    }
    __syncthreads();
  }
  if (tx < 10) {
    #pragma unroll
    for (int i=0;i<8;++i)
      #pragma unroll
      for (int j=0;j<4;++j)
        xdb[(size_t)(row0+ty*8+i)*40 + tx*4 + j] = acc[i][j];
  }
}

// ---------------- pass1: per-chunk local scan, 128-thr blocks (d-split) ----------------
__global__ __launch_bounds__(128,4) void k_pass1(
    const float* __restrict__ xdbf, const float* __restrict__ xdbb,
    const unsigned short* __restrict__ xcf, const unsigned short* __restrict__ xcb,
    const float* __restrict__ Wdtf, const float* __restrict__ Wdtb,
    const float* __restrict__ bdtf, const float* __restrict__ bdtb,
    const float* __restrict__ Alf, const float* __restrict__ Alb,
    float* __restrict__ sdtf, float* __restrict__ sdtb,
    float* __restrict__ hkf, float* __restrict__ hkb)
{
  const int dir = blockIdx.y;
  const float* __restrict__ xdb = dir ? xdbb : xdbf;
  const unsigned short* __restrict__ xc = dir ? xcb : xcf;
  const float* __restrict__ Wdt = dir ? Wdtb : Wdtf;
  const float* __restrict__ bdt = dir ? bdtb : bdtf;
  const float* __restrict__ Al  = dir ? Alb  : Alf;
  float* __restrict__ sdt = dir ? sdtb : sdtf;
  float* __restrict__ hk  = dir ? hkb  : hkf;
  const int dh = blockIdx.x & 1;
  const int cc = blockIdx.x >> 1;
  const int b = cc >> 7, c = cc & 127;
  const int t0 = c * LCn;
  __shared__ float S[LCn][24];
  const int tid = threadIdx.x;
  #pragma unroll
  for (int j=0;j<6;++j) {
    int idx = tid + j*128;
    int t = idx/24, jj = idx - t*24;
    S[t][jj] = xdb[(size_t)(b*Ln + t0 + t)*40 + jj];
  }
  const int d = dh*128 + tid;
  float Areg[16];
  #pragma unroll
  for (int s=0;s<16;++s) Areg[s] = -__expf(Al[d*16+s]);
  float wdt[8];
  #pragma unroll
  for (int j=0;j<8;++j) wdt[j] = Wdt[j*256+d];
  const float bd = bdt[d];
  float h[16];
  #pragma unroll
  for (int s=0;s<16;++s) h[s]=0.f;
  float sacc = 0.f;
  __syncthreads();
  #pragma unroll 2
  for (int t=0;t<LCn;++t) {
    float dtv = bd;
    #pragma unroll
    for (int j=0;j<8;++j) dtv = fmaf(S[t][j], wdt[j], dtv);
    dtv = softplusf(dtv);
    float xv = bf2f(xc[(size_t)(b*Ln + t0 + t)*256 + d]);
    float u = dtv * xv;
    sacc += dtv;
    #pragma unroll
    for (int s=0;s<16;++s)
      h[s] = fmaf(__expf(dtv*Areg[s]), h[s], u*S[t][8+s]);
  }
  sdt[(size_t)(b*NCn + c)*256 + d] = sacc;
  #pragma unroll
  for (int s=0;s<16;++s)
    hk[(size_t)((b*NCn + c)*16 + s)*256 + d] = h[s];
}

// ---------------- pass2: inter-chunk recurrence ----------------
__global__ __launch_bounds__(256) void k_pass2(
    const float* __restrict__ Alf, const float* __restrict__ Alb,
    const float* __restrict__ sdtf, const float* __restrict__ sdtb,
    float* __restrict__ hkf, float* __restrict__ hkb)
{
  const int dir = blockIdx.y;
  const float* __restrict__ Al  = dir ? Alb : Alf;
  const float* __restrict__ sdt = dir ? sdtb : sdtf;
  float* __restrict__ hk = dir ? hkb : hkf;
  int g = blockIdx.x*256 + threadIdx.x;
  int d = g & 255, s = (g >> 8) & 15, b = g >> 12;
  float Ad = -__expf(Al[d*16+s]);
  float h = 0.f;
  #pragma unroll 2
  for (int c=0;c<NCn;++c) {
    int bc = b*NCn + c;
    float sd = sdt[(size_t)bc*256 + d];
    size_t hi = (size_t)(bc*16 + s)*256 + d;
    float he = hk[hi];
    hk[hi] = h;
    h = fmaf(__expf(Ad*sd), h, he);
  }
}

// ---------------- pass3: replay; y+D*xc, gate silu(z) -> yg bf16 ----------------
__global__ __launch_bounds__(128,4) void k_pass3(
    const float* __restrict__ xdbf, const float* __restrict__ xdbb,
    const unsigned short* __restrict__ xcf, const unsigned short* __restrict__ xcb,
    const float* __restrict__ Wdtf, const float* __restrict__ Wdtb,
    const float* __restrict__ bdtf, const float* __restrict__ bdtb,
    const float* __restrict__ Alf, const float* __restrict__ Alb,
    const float* __restrict__ Dvf, const float* __restrict__ Dvb,
    const float* __restrict__ hkf, const float* __restrict__ hkb,
    const unsigned short* __restrict__ zbf, const unsigned short* __restrict__ zbb,
    unsigned short* __restrict__ ygf, unsigned short* __restrict__ ygb)
{
  const int dir = blockIdx.y;
  const float* __restrict__ xdb = dir ? xdbb : xdbf;
  const unsigned short* __restrict__ xc = dir ? xcb : xcf;
  const float* __restrict__ Wdt = dir ? Wdtb : Wdtf;
  const float* __restrict__ bdt = dir ? bdtb : bdtf;
  const float* __restrict__ Al  = dir ? Alb  : Alf;
  const float* __restrict__ Dv  = dir ? Dvb  : Dvf;
  const float* __restrict__ hk  = dir ? hkb  : hkf;
  const unsigned short* __restrict__ zbd = dir ? zbb : zbf;
  unsigned short* __restrict__ yg = dir ? ygb : ygf;
  const int dh = blockIdx.x & 1;
  const int cc = blockIdx.x >> 1;
  const int b = cc >> 7, c = cc & 127;
  const int t0 = c * LCn;
  __shared__ float S[LCn][40];
  const int tid = threadIdx.x;
  #pragma unroll
  for (int j=0;j<10;++j) {
    int idx = tid + j*128;
    int t = idx/40, jj = idx - t*40;
    S[t][jj] = xdb[(size_t)(b*Ln + t0 + t)*40 + jj];
  }
  const int d = dh*128 + tid;
  float Areg[16];
  #pragma unroll
  for (int s=0;s<16;++s) Areg[s] = -__expf(Al[d*16+s]);
  float wdt[8];
  #pragma unroll
  for (int j=0;j<8;++j) wdt[j] = Wdt[j*256+d];
  const float bd = bdt[d];
  const float Dd = Dv[d];
  float h[16];
  #pragma unroll
  for (int s=0;s<16;++s) h[s] = hk[(size_t)((b*NCn + c)*16 + s)*256 + d];
  __syncthreads();
  #pragma unroll 2
  for (int t=0;t<LCn;++t) {
    float dtv = bd;
    #pragma unroll
    for (int j=0;j<8;++j) dtv = fmaf(S[t][j], wdt[j], dtv);
    dtv = softplusf(dtv);
    size_t rowi = (size_t)(b*Ln + t0 + t);
    float xv = bf2f(xc[rowi*256 + d]);
    float u = dtv * xv;
    float y = 0.f;
    #pragma unroll
    for (int s=0;s<16;++s) {
      h[s] = fmaf(__expf(dtv*Areg[s]), h[s], u*S[t][8+s]);
      y = fmaf(h[s], S[t][24+s], y);
    }
    y = fmaf(Dd, xv, y);
    float zv = bf2f(zbd[rowi*256 + d]);
    yg[rowi*256 + d] = bfr(y * siluf(zv));
  }
}

// ---------------- Gout (bf16 MFMA): ypart[dir*2+khalf] = yg[dir] @ W_out[dir] (k-slice) --------
__global__ __launch_bounds__(256) void k_gout(
    const unsigned short* __restrict__ ygf, const unsigned short* __restrict__ ygb,
    const float* __restrict__ Wof, const float* __restrict__ Wob,
    float* __restrict__ yp)
{
  const int row0 = blockIdx.x * 128;
  const int khalf = blockIdx.y;
  const int dir = blockIdx.z;
  const unsigned short* __restrict__ ygd = dir ? ygb : ygf;
  const float* __restrict__ Wod = dir ? Wob : Wof;
  float* __restrict__ ypart = yp + (size_t)(dir*2 + khalf) * ROWS * 128;
  const int b = row0 >> 12;
  const int l0 = row0 & (Ln-1);

  __shared__ __align__(16) char smem[SMEMB];
  short* Ast = (short*)smem;
  short* Bst = (short*)smem + 8*512;
  float* Te  = (float*)smem;

  const int tid = threadIdx.x;
  const int lane = tid & 63;
  const int wid = tid >> 6;
  const int wr = wid >> 1, wc = wid & 1;
  const int r16 = lane & 15, kg = lane >> 4;

  // A staging: row ar, k-half kh (16 k each, 2 granules)
  const int ar = tid >> 1, kh = tid & 1;
  // B staging: 4 n (q) x 4 k (kq)
  const int q = tid & 31, kq = tid >> 5;
  const int kbase = 4*kq;
  const int g_true = kq >> 1;
  const int ghalf = (kq & 1) * 4;

  f4v acc[4][4];
  #pragma unroll
  for (int i=0;i<4;++i)
    #pragma unroll
    for (int j=0;j<4;++j) acc[i][j] = (f4v){0.f,0.f,0.f,0.f};

  for (int ks=0; ks<4; ++ks) {
    const int kk0 = khalf*128 + ks*32;
    if (ks) __syncthreads();
    // ---- stage A: direct bf16 copy (no converts)
    {
      int rl = l0 + ar;
      size_t srow = (size_t)b*Ln + (dir ? (Ln-1-rl) : rl);
      const unsigned short* s = ygd + srow*256 + kk0 + kh*16;
      u8v u0 = *(const u8v*)(s);
      u8v u1 = *(const u8v*)(s + 8);
      int o0 = tile_off(ar, 2*kh,   0);
      int o1 = tile_off(ar, 2*kh+1, 0);
      *(u8v*)&Ast[o0] = u0;
      *(u8v*)&Ast[o1] = u1;
    }
    // ---- stage B: W_out f32 -> bf16
    {
      float4 vb[4];
      #pragma unroll
      for (int kk=0;kk<4;++kk)
        vb[kk] = *(const float4*)(Wod + (size_t)(kk0+kbase+kk)*128 + 4*q);
      #pragma unroll
      for (int e=0;e<4;++e) {
        int r = 4*q + e;
        int off = tile_off(r, g_true, ghalf);
        s4v hv;
        #pragma unroll
        for (int kk=0;kk<4;++kk) hv[kk] = (short)bfr(((const float*)&vb[kk])[e]);
        *(s4v*)&Bst[off] = hv;
      }
    }
    __syncthreads();
    const int gsh = ((kg ^ ((r16>>1)&3)) << 3);
    s8v fa[4], fb[4];
    #pragma unroll
    for (int m=0;m<4;++m) fa[m] = *(const s8v*)&Ast[(wr*4+m)*512 + r16*32 + gsh];
    #pragma unroll
    for (int n=0;n<4;++n) fb[n] = *(const s8v*)&Bst[(wc*4+n)*512 + r16*32 + gsh];
    #pragma unroll
    for (int m=0;m<4;++m)
      #pragma unroll
      for (int n=0;n<4;++n)
        acc[m][n] = __builtin_amdgcn_mfma_f32_16x16x32_bf16(fa[m], fb[n], acc[m][n], 0,0,0);
  }
  // ---- epilogue: LDS transpose -> float4 stores
  __syncthreads();
  float* Tw = Te + wid*1088;
  #pragma unroll
  for (int m=0;m<4;++m) {
    #pragma unroll
    for (int n=0;n<4;++n)
      #pragma unroll
      for (int v=0;v<4;++v)
        Tw[(kg*4+v)*68 + n*16 + r16] = acc[m][n][v];
    #pragma unroll
    for (int rr=0;rr<4;++rr) {
      int r = rr*4 + (lane>>4);
      int c4 = lane & 15;
      float4 v4 = *(const float4*)&Tw[r*68 + c4*4];
      int row = row0 + wr*64 + m*16 + r;
      *(float4*)(ypart + (size_t)row*128 + wc*64 + c4*4) = v4;
    }
  }
}

// ---------------- GroupNorm stats + partial-sum -> ysum ----------------
__global__ __launch_bounds__(256) void k_gnstat(const float* __restrict__ yp,
    float* __restrict__ ysum, float* __restrict__ part)
{
  const int bg = blockIdx.x >> 4;
  const int blk = blockIdx.x & 15;
  const int b = bg >> 2, g = bg & 3;
  const size_t P = (size_t)ROWS*128;
  float s=0.f, q=0.f;
  #pragma unroll
  for (int i=0;i<8;++i) {
    int e4 = blk*2048 + threadIdx.x + i*256;
    int l = e4 >> 3, c4 = e4 & 7;
    size_t base = (size_t)(b*Ln + l)*128 + g*32 + c4*4;
    float4 v0 = *(const float4*)(yp + base);
    float4 v1 = *(const float4*)(yp + P + base);
    float4 v2 = *(const float4*)(yp + 2*P + base);
    float4 v3 = *(const float4*)(yp + 3*P + base);
    float4 v;
    v.x = v0.x+v1.x+v2.x+v3.x;
    v.y = v0.y+v1.y+v2.y+v3.y;
    v.z = v0.z+v1.z+v2.z+v3.z;
    v.w = v0.w+v1.w+v2.w+v3.w;
    *(float4*)(ysum + base) = v;
    s += v.x+v.y+v.z+v.w;
    q = fmaf(v.x,v.x, fmaf(v.y,v.y, fmaf(v.z,v.z, fmaf(v.w,v.w, q))));
  }
  __shared__ float rs[256], rq[256];
  rs[threadIdx.x]=s; rq[threadIdx.x]=q;
  __syncthreads();
  for (int off=128; off>0; off>>=1) {
    if (threadIdx.x < off) { rs[threadIdx.x]+=rs[threadIdx.x+off]; rq[threadIdx.x]+=rq[threadIdx.x+off]; }
    __syncthreads();
  }
  if (threadIdx.x==0) { part[blockIdx.x*2]=rs[0]; part[blockIdx.x*2+1]=rq[0]; }
}

__global__ void k_gnred(const float* __restrict__ part, float* __restrict__ mr)
{
  int t = threadIdx.x;
  if (t < 16) {
    float s=0.f,q=0.f;
    for (int k=0;k<16;++k){ s+=part[(t*16+k)*2]; q+=part[(t*16+k)*2+1]; }
    const float inv = 1.f/131072.f;
    float mean = s*inv;
    float var = fmaf(-mean, mean, q*inv);
    mr[t*2] = mean;
    mr[t*2+1] = rsqrtf(var + 1e-5f);
  }
}

// ---------------- GN apply + silu + residual ----------------
__global__ __launch_bounds__(256) void k_gnapply(const float* __restrict__ ysum,
    const float* __restrict__ mr, const float* __restrict__ gamma, const float* __restrict__ beta,
    const float* __restrict__ x, float* __restrict__ out)
{
  const int b = blockIdx.x >> 6;
  const int l0 = (blockIdx.x & 63) * 64;
  __shared__ float T[64][132];
  const int tid = threadIdx.x;
  #pragma unroll
  for (int j=0;j<8;++j) {
    int f = tid + j*256;
    int l = f >> 5, c4 = f & 31;
    *(float4*)&T[l][c4*4] = *(const float4*)(ysum + (size_t)(b*Ln + l0 + l)*128 + c4*4);
  }
  __syncthreads();
  #pragma unroll
  for (int j=0;j<8;++j) {
    int f = tid + j*256;
    int c = f >> 4, lv = f & 15;
    int bg = b*4 + (c>>5);
    float mean = mr[bg*2];
    float rstd = mr[bg*2+1];
    float gam = gamma[c], bet = beta[c];
    size_t base = (size_t)(b*Cn + c)*Ln + l0 + lv*4;
    float4 xv = *(const float4*)(x + base);
    float4 r;
    r.x = siluf(fmaf((T[lv*4+0][c]-mean)*rstd, gam, bet)) + xv.x;
    r.y = siluf(fmaf((T[lv*4+1][c]-mean)*rstd, gam, bet)) + xv.y;
    r.z = siluf(fmaf((T[lv*4+2][c]-mean)*rstd, gam, bet)) + xv.z;
    r.w = siluf(fmaf((T[lv*4+3][c]-mean)*rstd, gam, bet)) + xv.w;
    *(float4*)(out + base) = r;
  }
}

extern "C" void kernel_launch(void* const* d_in, const int* in_sizes, int n_in,
                              void* d_out, int out_size, void* d_ws, size_t ws_size,
                              hipStream_t stream) {
  const float* x      = (const float*)d_in[0];
  const float* W_in_f = (const float*)d_in[1];
  const float* cw_f   = (const float*)d_in[2];
  const float* cb_f   = (const float*)d_in[3];
  const float* Wx_f   = (const float*)d_in[4];
  const float* Wdt_f  = (const float*)d_in[5];
  const float* bdt_f  = (const float*)d_in[6];
  const float* Al_f   = (const float*)d_in[7];
  const float* D_f    = (const float*)d_in[8];
  const float* Wo_f   = (const float*)d_in[9];
  const float* W_in_b = (const float*)d_in[10];
  const float* cw_b   = (const float*)d_in[11];
  const float* cb_b   = (const float*)d_in[12];
  const float* Wx_b   = (const float*)d_in[13];
  const float* Wdt_b  = (const float*)d_in[14];
  const float* bdt_b  = (const float*)d_in[15];
  const float* Al_b   = (const float*)d_in[16];
  const float* D_b    = (const float*)d_in[17];
  const float* Wo_b   = (const float*)d_in[18];
  const float* gamma  = (const float*)d_in[19];
  const float* beta   = (const float*)d_in[20];
  float* out = (float*)d_out;

  float* w = (float*)d_ws;
  size_t o = 0;
  float* xp0 = w + o; o += (size_t)ROWS*256;       // f32, dead after conv -> ypart alias
  float* xp1 = w + o; o += (size_t)ROWS*256;
  unsigned short* xc0 = (unsigned short*)(w + o); o += (size_t)ROWS*128;  // bf16
  unsigned short* xc1 = (unsigned short*)(w + o); o += (size_t)ROWS*128;
  unsigned short* zb0 = (unsigned short*)(w + o); o += (size_t)ROWS*128;  // bf16
  unsigned short* zb1 = (unsigned short*)(w + o); o += (size_t)ROWS*128;
  unsigned short* yg0 = (unsigned short*)(w + o); o += (size_t)ROWS*128;  // bf16
  unsigned short* yg1 = (unsigned short*)(w + o); o += (size_t)ROWS*128;
  float* xdb0 = w + o; o += (size_t)ROWS*40;       // dead after pass3 -> ysum alias
  float* xdb1 = w + o; o += (size_t)ROWS*40;
  float* sdt0 = w + o; o += (size_t)Bn*NCn*256;
  float* sdt1 = w + o; o += (size_t)Bn*NCn*256;
  float* hk0  = w + o; o += (size_t)Bn*NCn*16*256;
  float* hk1  = w + o; o += (size_t)Bn*NCn*16*256;
  float* part = w + o; o += 512;
  float* mr   = w + o; o += 32;
  float* yp   = xp0;    // 4 partials x ROWS*128 = 8.39M floats <= xp0+xp1 (8.39M)
  float* ysum = xdb0;   // 2.1M floats <= dead xdb/sdt/hk region (5.77M)
  if (ws_size < o*sizeof(float)) return;

  k_g1<<<dim3(ROWS/128, 4, 2), 256, 0, stream>>>(x, W_in_f, W_in_b, xp0, xp1, zb0, zb1);
  k_conv<<<dim3(1024, 2), 256, 0, stream>>>(xp0, xp1, cw_f, cw_b, cb_f, cb_b, xc0, xc1);
  k_g2<<<dim3(ROWS/128, 1, 2), 256, 0, stream>>>(xc0, xc1, Wx_f, Wx_b, xdb0, xdb1);
  k_pass1<<<dim3(Bn*NCn*2, 2), 128, 0, stream>>>(xdb0, xdb1, xc0, xc1, Wdt_f, Wdt_b,
                                                 bdt_f, bdt_b, Al_f, Al_b, sdt0, sdt1, hk0, hk1);
  k_pass2<<<dim3(64, 2), 256, 0, stream>>>(Al_f, Al_b, sdt0, sdt1, hk0, hk1);
  k_pass3<<<dim3(Bn*NCn*2, 2), 128, 0, stream>>>(xdb0, xdb1, xc0, xc1, Wdt_f, Wdt_b,
                                                 bdt_f, bdt_b, Al_f, Al_b, D_f, D_b,
                                                 hk0, hk1, zb0, zb1, yg0, yg1);
  k_gout<<<dim3(ROWS/128, 2, 2), 256, 0, stream>>>(yg0, yg1, Wo_f, Wo_b, yp);
  k_gnstat<<<dim3(256), 256, 0, stream>>>(yp, ysum, part);
  k_gnred<<<dim3(1), 64, 0, stream>>>(part, mr);
  k_gnapply<<<dim3(256), 256, 0, stream>>>(ysum, mr, gamma, beta, x, out);
}

// Round 7
// 183.715 us; speedup vs baseline: 1.2439x; 1.0865x over previous
//
#include <hip/hip_runtime.h>

#define Bn 4
#define Ln 4096
#define Cn 128
#define DIn 256
#define NCn 128
#define LCn 32
#define ROWS (Bn*Ln)

typedef short s8v __attribute__((ext_vector_type(8)));
typedef short s4v __attribute__((ext_vector_type(4)));
typedef unsigned short u8v __attribute__((ext_vector_type(8)));
typedef unsigned short u4v __attribute__((ext_vector_type(4)));
typedef float f4v __attribute__((ext_vector_type(4)));

__device__ __forceinline__ float siluf(float x){ return x / (1.f + __expf(-x)); }
__device__ __forceinline__ unsigned short bfr(float f){
  uint u = __float_as_uint(f);
  return (unsigned short)((u + 0x7fffu + ((u>>16)&1u)) >> 16);
}
__device__ __forceinline__ float bf2f(unsigned short u){ return __uint_as_float(((uint)u)<<16); }

// dt = softplus(r); w = exp(-dt) = sigmoid(-r). 3 trans ops total.
__device__ __forceinline__ void sp_w(float r, float& dtv, float& w){
  float e = __expf(-fabsf(r));
  float rc = 1.f / (1.f + e);
  dtv = fmaxf(r, 0.f) + __logf(1.f + e);
  w = (r > 0.f) ? e * rc : rc;
}

// LDS tile layout (128x32 bf16 tile): 8 subtiles [16r][32k]; granule (8 shorts)
// XOR-swizzled by ((r>>1)&3) -> wave s8v reads are ~2-way bank-aliased (free, m136).
__device__ __forceinline__ int tile_off(int r, int gran, int ghalf){
  return ((r>>4)<<9) + ((r&15)<<5) + (((gran ^ ((r>>1)&3)))<<3) + ghalf;
}

#define SMEMB 18432

// ---------------- G1 (bf16 MFMA): xz = (dir? rev xs : xs) @ W_in ----------------
__global__ __launch_bounds__(256) void k_g1(const float* __restrict__ x,
    const float* __restrict__ Wf, const float* __restrict__ Wb,
    float* __restrict__ xpf, float* __restrict__ xpb,
    unsigned short* __restrict__ zbf, unsigned short* __restrict__ zbb)
{
  const int dir = blockIdx.z;
  const float* __restrict__ W = dir ? Wb : Wf;
  float* __restrict__ xp = dir ? xpb : xpf;
  unsigned short* __restrict__ zb = dir ? zbb : zbf;
  const int row0 = blockIdx.x * 128;
  const int n0 = blockIdx.y;
  const int b = row0 >> 12;
  const int t0 = row0 & (Ln-1);
  const float* __restrict__ xb = x + (size_t)b * Cn * Ln;

  __shared__ __align__(16) char smem[SMEMB];
  short* Ast = (short*)smem;
  short* Bst = (short*)smem + 8*512;
  float* Te  = (float*)smem;

  const int tid = threadIdx.x;
  const int lane = tid & 63;
  const int wid = tid >> 6;
  const int wr = wid >> 1, wc = wid & 1;
  const int r16 = lane & 15, kg = lane >> 4;

  const int q = tid & 31, kq = tid >> 5;
  const int kbase = 4*kq;
  const int g_true = kq >> 1;
  const int ghalf = (kq & 1) * 4;

  f4v acc[4][4];
  #pragma unroll
  for (int i=0;i<4;++i)
    #pragma unroll
    for (int j=0;j<4;++j) acc[i][j] = (f4v){0.f,0.f,0.f,0.f};

  float4 va[4], vb[4];
  {
    #pragma unroll
    for (int kk=0;kk<4;++kk) {
      va[kk] = (dir==0)
        ? *(const float4*)(xb + (size_t)(kbase+kk)*Ln + t0 + 4*q)
        : *(const float4*)(xb + (size_t)(kbase+kk)*Ln + (Ln-4 - t0 - 4*q));
      vb[kk] = *(const float4*)(W + (size_t)(kbase+kk)*512 + n0*128 + 4*q);
    }
  }
  for (int ks=0; ks<4; ++ks) {
    if (ks) __syncthreads();
    #pragma unroll
    for (int e=0;e<4;++e) {
      int r = 4*q + e;
      int off = tile_off(r, g_true, ghalf);
      int c = dir ? (3-e) : e;
      s4v hv;
      #pragma unroll
      for (int kk=0;kk<4;++kk) hv[kk] = (short)bfr(((const float*)&va[kk])[c]);
      *(s4v*)&Ast[off] = hv;
    }
    #pragma unroll
    for (int e=0;e<4;++e) {
      int r = 4*q + e;
      int off = tile_off(r, g_true, ghalf);
      s4v hv;
      #pragma unroll
      for (int kk=0;kk<4;++kk) hv[kk] = (short)bfr(((const float*)&vb[kk])[e]);
      *(s4v*)&Bst[off] = hv;
    }
    __syncthreads();
    if (ks < 3) {
      const int k0n = (ks+1)*32;
      #pragma unroll
      for (int kk=0;kk<4;++kk) {
        va[kk] = (dir==0)
          ? *(const float4*)(xb + (size_t)(k0n+kbase+kk)*Ln + t0 + 4*q)
          : *(const float4*)(xb + (size_t)(k0n+kbase+kk)*Ln + (Ln-4 - t0 - 4*q));
        vb[kk] = *(const float4*)(W + (size_t)(k0n+kbase+kk)*512 + n0*128 + 4*q);
      }
    }
    const int gsh = ((kg ^ ((r16>>1)&3)) << 3);
    s8v fa[4], fb[4];
    #pragma unroll
    for (int m=0;m<4;++m) fa[m] = *(const s8v*)&Ast[(wr*4+m)*512 + r16*32 + gsh];
    #pragma unroll
    for (int n=0;n<4;++n) fb[n] = *(const s8v*)&Bst[(wc*4+n)*512 + r16*32 + gsh];
    #pragma unroll
    for (int m=0;m<4;++m)
      #pragma unroll
      for (int n=0;n<4;++n)
        acc[m][n] = __builtin_amdgcn_mfma_f32_16x16x32_bf16(fa[m], fb[n], acc[m][n], 0,0,0);
  }
  __syncthreads();
  float* Tw = Te + wid*1088;
  #pragma unroll
  for (int m=0;m<4;++m) {
    #pragma unroll
    for (int n=0;n<4;++n)
      #pragma unroll
      for (int v=0;v<4;++v)
        Tw[(kg*4+v)*68 + n*16 + r16] = acc[m][n][v];
    #pragma unroll
    for (int rr=0;rr<4;++rr) {
      int r = rr*4 + (lane>>4);
      int c4 = lane & 15;
      float4 v4 = *(const float4*)&Tw[r*68 + c4*4];
      int row = row0 + wr*64 + m*16 + r;
      int colL = wc*64 + c4*4;
      if (n0 < 2) {
        *(float4*)(xp + (size_t)row*256 + n0*128 + colL) = v4;
      } else {
        u4v u; u[0]=bfr(v4.x); u[1]=bfr(v4.y); u[2]=bfr(v4.z); u[3]=bfr(v4.w);
        *(u4v*)(zb + (size_t)row*256 + (n0-2)*128 + colL) = u;
      }
    }
  }
}

// ---------------- conv: xc = silu(conv) -> bf16 ----------------
__global__ __launch_bounds__(256) void k_conv(
    const float* __restrict__ xpf, const float* __restrict__ xpb,
    const float* __restrict__ cwf, const float* __restrict__ cwb,
    const float* __restrict__ cbf, const float* __restrict__ cbb,
    unsigned short* __restrict__ xcf, unsigned short* __restrict__ xcb)
{
  const int dir = blockIdx.y;
  const float* __restrict__ xpd = dir ? xpb : xpf;
  const float* __restrict__ cw = dir ? cwb : cwf;
  const float* __restrict__ cb = dir ? cbb : cbf;
  unsigned short* __restrict__ xc = dir ? xcb : xcf;
  const int n4 = ROWS * 64;
  for (int idx4 = blockIdx.x*256 + threadIdx.x; idx4 < n4; idx4 += gridDim.x*256) {
    int row = idx4 >> 6;
    int d0 = (idx4 & 63) * 4;
    float4 cur = *(const float4*)(xpd + (size_t)row*256 + d0);
    float4 prev = make_float4(0.f,0.f,0.f,0.f);
    if (row & (Ln-1)) prev = *(const float4*)(xpd + (size_t)(row-1)*256 + d0);
    float4 cwA = *(const float4*)(cw + d0*2);
    float4 cwB = *(const float4*)(cw + d0*2 + 4);
    float4 cb4 = *(const float4*)(cb + d0);
    u4v r;
    r[0] = bfr(siluf(fmaf(prev.x,cwA.x, fmaf(cur.x,cwA.y, cb4.x))));
    r[1] = bfr(siluf(fmaf(prev.y,cwA.z, fmaf(cur.y,cwA.w, cb4.y))));
    r[2] = bfr(siluf(fmaf(prev.z,cwB.x, fmaf(cur.z,cwB.y, cb4.z))));
    r[3] = bfr(siluf(fmaf(prev.w,cwB.z, fmaf(cur.w,cwB.w, cb4.w))));
    *(u4v*)(xc + (size_t)row*256 + d0) = r;
  }
}

// ---------------- G2: xdb = xc @ W_x ----------------
__global__ __launch_bounds__(256) void k_g2(
    const unsigned short* __restrict__ xcf, const unsigned short* __restrict__ xcb,
    const float* __restrict__ Wxf, const float* __restrict__ Wxb,
    float* __restrict__ xdbf, float* __restrict__ xdbb)
{
  const int dir = blockIdx.z;
  const unsigned short* __restrict__ xc = dir ? xcb : xcf;
  const float* __restrict__ Wx = dir ? Wxb : Wxf;
  float* __restrict__ xdb = dir ? xdbb : xdbf;
  const int row0 = blockIdx.x * 128;
  __shared__ float As[16][132];
  __shared__ float Bs[16][64];
  const int tid = threadIdx.x;
  const int tx = tid & 15, ty = tid >> 4;
  float acc[8][4];
  #pragma unroll
  for (int i=0;i<8;++i)
    #pragma unroll
    for (int j=0;j<4;++j) acc[i][j]=0.f;

  for (int k0 = 0; k0 < 256; k0 += 16) {
    {
      int r = tid >> 1, half = tid & 1;
      u8v u = *(const u8v*)(xc + (size_t)(row0+r)*256 + k0 + half*8);
      #pragma unroll
      for (int i=0;i<8;++i) As[half*8+i][r] = bf2f(u[i]);
    }
    #pragma unroll
    for (int j = 0; j < 4; ++j) {
      int idx = tid + j*256;
      int k = idx >> 6, n = idx & 63;
      Bs[k][n] = (n < 40) ? Wx[(size_t)(k0+k)*40 + n] : 0.f;
    }
    __syncthreads();
    #pragma unroll
    for (int kk=0;kk<16;++kk) {
      float a[8], bv[4];
      *(float4*)&a[0] = *(const float4*)&As[kk][ty*8];
      *(float4*)&a[4] = *(const float4*)&As[kk][ty*8+4];
      *(float4*)&bv[0] = *(const float4*)&Bs[kk][tx*4];
      #pragma unroll
      for (int i=0;i<8;++i)
        #pragma unroll
        for (int j=0;j<4;++j) acc[i][j] = fmaf(a[i], bv[j], acc[i][j]);
    }
    __syncthreads();
  }
  if (tx < 10) {
    #pragma unroll
    for (int i=0;i<8;++i)
      #pragma unroll
      for (int j=0;j<4;++j)
        xdb[(size_t)(row0+ty*8+i)*40 + tx*4 + j] = acc[i][j];
  }
}

// ---------------- pass1: per-chunk local scan; structured-A fast path ----------------
__global__ __launch_bounds__(128,4) void k_pass1(
    const float* __restrict__ xdbf, const float* __restrict__ xdbb,
    const unsigned short* __restrict__ xcf, const unsigned short* __restrict__ xcb,
    const float* __restrict__ Wdtf, const float* __restrict__ Wdtb,
    const float* __restrict__ bdtf, const float* __restrict__ bdtb,
    const float* __restrict__ Alf, const float* __restrict__ Alb,
    float* __restrict__ sdtf, float* __restrict__ sdtb,
    float* __restrict__ hkf, float* __restrict__ hkb)
{
  const int dir = blockIdx.y;
  const float* __restrict__ xdb = dir ? xdbb : xdbf;
  const unsigned short* __restrict__ xc = dir ? xcb : xcf;
  const float* __restrict__ Wdt = dir ? Wdtb : Wdtf;
  const float* __restrict__ bdt = dir ? bdtb : bdtf;
  const float* __restrict__ Al  = dir ? Alb  : Alf;
  float* __restrict__ sdt = dir ? sdtb : sdtf;
  float* __restrict__ hk  = dir ? hkb  : hkf;
  const int dh = blockIdx.x & 1;
  const int cc = blockIdx.x >> 1;
  const int b = cc >> 7, c = cc & 127;
  const int t0 = c * LCn;
  __shared__ float S[LCn][24];
  const int tid = threadIdx.x;
  #pragma unroll
  for (int j=0;j<6;++j) {
    int idx = tid + j*128;
    int t = idx/24, jj = idx - t*24;
    S[t][jj] = xdb[(size_t)(b*Ln + t0 + t)*40 + jj];
  }
  const int d = dh*128 + tid;
  float Areg[16];
  bool st = true;
  #pragma unroll
  for (int s=0;s<16;++s) {
    Areg[s] = -__expf(Al[d*16+s]);
    st = st && (fabsf(Areg[s] + (float)(s+1)) <= 3e-5f*(float)(s+1));
  }
  float wdt[8];
  #pragma unroll
  for (int j=0;j<8;++j) wdt[j] = Wdt[j*256+d];
  const float bd = bdt[d];
  float h[16];
  #pragma unroll
  for (int s=0;s<16;++s) h[s]=0.f;
  float sacc = 0.f;
  __syncthreads();
  if (st) {
    #pragma unroll 2
    for (int t=0;t<LCn;++t) {
      float r = bd;
      #pragma unroll
      for (int j=0;j<8;++j) r = fmaf(S[t][j], wdt[j], r);
      float dtv, w;
      sp_w(r, dtv, w);
      float xv = bf2f(xc[(size_t)(b*Ln + t0 + t)*256 + d]);
      float u = dtv * xv;
      sacc += dtv;
      float wp = w;
      #pragma unroll
      for (int s=0;s<16;++s) {
        h[s] = fmaf(h[s], wp, u*S[t][8+s]);
        wp *= w;
      }
    }
  } else {
    #pragma unroll 2
    for (int t=0;t<LCn;++t) {
      float r = bd;
      #pragma unroll
      for (int j=0;j<8;++j) r = fmaf(S[t][j], wdt[j], r);
      float dtv, w;
      sp_w(r, dtv, w);
      float xv = bf2f(xc[(size_t)(b*Ln + t0 + t)*256 + d]);
      float u = dtv * xv;
      sacc += dtv;
      #pragma unroll
      for (int s=0;s<16;++s)
        h[s] = fmaf(h[s], __expf(dtv*Areg[s]), u*S[t][8+s]);
    }
  }
  sdt[(size_t)(b*NCn + c)*256 + d] = sacc;
  #pragma unroll
  for (int s=0;s<16;++s)
    hk[(size_t)((b*NCn + c)*16 + s)*256 + d] = h[s];
}

// ---------------- pass2: inter-chunk recurrence ----------------
__global__ __launch_bounds__(256) void k_pass2(
    const float* __restrict__ Alf, const float* __restrict__ Alb,
    const float* __restrict__ sdtf, const float* __restrict__ sdtb,
    float* __restrict__ hkf, float* __restrict__ hkb)
{
  const int dir = blockIdx.y;
  const float* __restrict__ Al  = dir ? Alb : Alf;
  const float* __restrict__ sdt = dir ? sdtb : sdtf;
  float* __restrict__ hk = dir ? hkb : hkf;
  int g = blockIdx.x*256 + threadIdx.x;
  int d = g & 255, s = (g >> 8) & 15, b = g >> 12;
  float Ad = -__expf(Al[d*16+s]);
  float h = 0.f;
  #pragma unroll 2
  for (int c=0;c<NCn;++c) {
    int bc = b*NCn + c;
    float sd = sdt[(size_t)bc*256 + d];
    size_t hi = (size_t)(bc*16 + s)*256 + d;
    float he = hk[hi];
    hk[hi] = h;
    h = fmaf(__expf(Ad*sd), h, he);
  }
}

// ---------------- pass3: replay; y+D*xc, gate silu(z) -> yg bf16; structured-A fast path ----
__global__ __launch_bounds__(128,4) void k_pass3(
    const float* __restrict__ xdbf, const float* __restrict__ xdbb,
    const unsigned short* __restrict__ xcf, const unsigned short* __restrict__ xcb,
    const float* __restrict__ Wdtf, const float* __restrict__ Wdtb,
    const float* __restrict__ bdtf, const float* __restrict__ bdtb,
    const float* __restrict__ Alf, const float* __restrict__ Alb,
    const float* __restrict__ Dvf, const float* __restrict__ Dvb,
    const float* __restrict__ hkf, const float* __restrict__ hkb,
    const unsigned short* __restrict__ zbf, const unsigned short* __restrict__ zbb,
    unsigned short* __restrict__ ygf, unsigned short* __restrict__ ygb)
{
  const int dir = blockIdx.y;
  const float* __restrict__ xdb = dir ? xdbb : xdbf;
  const unsigned short* __restrict__ xc = dir ? xcb : xcf;
  const float* __restrict__ Wdt = dir ? Wdtb : Wdtf;
  const float* __restrict__ bdt = dir ? bdtb : bdtf;
  const float* __restrict__ Al  = dir ? Alb  : Alf;
  const float* __restrict__ Dv  = dir ? Dvb  : Dvf;
  const float* __restrict__ hk  = dir ? hkb  : hkf;
  const unsigned short* __restrict__ zbd = dir ? zbb : zbf;
  unsigned short* __restrict__ yg = dir ? ygb : ygf;
  const int dh = blockIdx.x & 1;
  const int cc = blockIdx.x >> 1;
  const int b = cc >> 7, c = cc & 127;
  const int t0 = c * LCn;
  __shared__ float S[LCn][40];
  const int tid = threadIdx.x;
  #pragma unroll
  for (int j=0;j<10;++j) {
    int idx = tid + j*128;
    int t = idx/40, jj = idx - t*40;
    S[t][jj] = xdb[(size_t)(b*Ln + t0 + t)*40 + jj];
  }
  const int d = dh*128 + tid;
  float Areg[16];
  bool st = true;
  #pragma unroll
  for (int s=0;s<16;++s) {
    Areg[s] = -__expf(Al[d*16+s]);
    st = st && (fabsf(Areg[s] + (float)(s+1)) <= 3e-5f*(float)(s+1));
  }
  float wdt[8];
  #pragma unroll
  for (int j=0;j<8;++j) wdt[j] = Wdt[j*256+d];
  const float bd = bdt[d];
  const float Dd = Dv[d];
  float h[16];
  #pragma unroll
  for (int s=0;s<16;++s) h[s] = hk[(size_t)((b*NCn + c)*16 + s)*256 + d];
  __syncthreads();
  if (st) {
    #pragma unroll 2
    for (int t=0;t<LCn;++t) {
      float r = bd;
      #pragma unroll
      for (int j=0;j<8;++j) r = fmaf(S[t][j], wdt[j], r);
      float dtv, w;
      sp_w(r, dtv, w);
      size_t rowi = (size_t)(b*Ln + t0 + t);
      float xv = bf2f(xc[rowi*256 + d]);
      float u = dtv * xv;
      float y = 0.f;
      float wp = w;
      #pragma unroll
      for (int s=0;s<16;++s) {
        h[s] = fmaf(h[s], wp, u*S[t][8+s]);
        y = fmaf(h[s], S[t][24+s], y);
        wp *= w;
      }
      y = fmaf(Dd, xv, y);
      float zv = bf2f(zbd[rowi*256 + d]);
      yg[rowi*256 + d] = bfr(y * siluf(zv));
    }
  } else {
    #pragma unroll 2
    for (int t=0;t<LCn;++t) {
      float r = bd;
      #pragma unroll
      for (int j=0;j<8;++j) r = fmaf(S[t][j], wdt[j], r);
      float dtv, w;
      sp_w(r, dtv, w);
      size_t rowi = (size_t)(b*Ln + t0 + t);
      float xv = bf2f(xc[rowi*256 + d]);
      float u = dtv * xv;
      float y = 0.f;
      #pragma unroll
      for (int s=0;s<16;++s) {
        h[s] = fmaf(h[s], __expf(dtv*Areg[s]), u*S[t][8+s]);
        y = fmaf(h[s], S[t][24+s], y);
      }
      y = fmaf(Dd, xv, y);
      float zv = bf2f(zbd[rowi*256 + d]);
      yg[rowi*256 + d] = bfr(y * siluf(zv));
    }
  }
}

// ---------------- Gout (bf16 MFMA): ypart[dir*2+khalf] = yg[dir] @ W_out[dir] ----------------
__global__ __launch_bounds__(256) void k_gout(
    const unsigned short* __restrict__ ygf, const unsigned short* __restrict__ ygb,
    const float* __restrict__ Wof, const float* __restrict__ Wob,
    float* __restrict__ yp)
{
  const int row0 = blockIdx.x * 128;
  const int khalf = blockIdx.y;
  const int dir = blockIdx.z;
  const unsigned short* __restrict__ ygd = dir ? ygb : ygf;
  const float* __restrict__ Wod = dir ? Wob : Wof;
  float* __restrict__ ypart = yp + (size_t)(dir*2 + khalf) * ROWS * 128;
  const int b = row0 >> 12;
  const int l0 = row0 & (Ln-1);

  __shared__ __align__(16) char smem[SMEMB];
  short* Ast = (short*)smem;
  short* Bst = (short*)smem + 8*512;
  float* Te  = (float*)smem;

  const int tid = threadIdx.x;
  const int lane = tid & 63;
  const int wid = tid >> 6;
  const int wr = wid >> 1, wc = wid & 1;
  const int r16 = lane & 15, kg = lane >> 4;

  const int ar = tid >> 1, kh = tid & 1;
  const int q = tid & 31, kq = tid >> 5;
  const int kbase = 4*kq;
  const int g_true = kq >> 1;
  const int ghalf = (kq & 1) * 4;

  f4v acc[4][4];
  #pragma unroll
  for (int i=0;i<4;++i)
    #pragma unroll
    for (int j=0;j<4;++j) acc[i][j] = (f4v){0.f,0.f,0.f,0.f};

  for (int ks=0; ks<4; ++ks) {
    const int kk0 = khalf*128 + ks*32;
    if (ks) __syncthreads();
    {
      int rl = l0 + ar;
      size_t srow = (size_t)b*Ln + (dir ? (Ln-1-rl) : rl);
      const unsigned short* s = ygd + srow*256 + kk0 + kh*16;
      u8v u0 = *(const u8v*)(s);
      u8v u1 = *(const u8v*)(s + 8);
      int o0 = tile_off(ar, 2*kh,   0);
      int o1 = tile_off(ar, 2*kh+1, 0);
      *(u8v*)&Ast[o0] = u0;
      *(u8v*)&Ast[o1] = u1;
    }
    {
      float4 vb[4];
      #pragma unroll
      for (int kk=0;kk<4;++kk)
        vb[kk] = *(const float4*)(Wod + (size_t)(kk0+kbase+kk)*128 + 4*q);
      #pragma unroll
      for (int e=0;e<4;++e) {
        int r = 4*q + e;
        int off = tile_off(r, g_true, ghalf);
        s4v hv;
        #pragma unroll
        for (int kk=0;kk<4;++kk) hv[kk] = (short)bfr(((const float*)&vb[kk])[e]);
        *(s4v*)&Bst[off] = hv;
      }
    }
    __syncthreads();
    const int gsh = ((kg ^ ((r16>>1)&3)) << 3);
    s8v fa[4], fb[4];
    #pragma unroll
    for (int m=0;m<4;++m) fa[m] = *(const s8v*)&Ast[(wr*4+m)*512 + r16*32 + gsh];
    #pragma unroll
    for (int n=0;n<4;++n) fb[n] = *(const s8v*)&Bst[(wc*4+n)*512 + r16*32 + gsh];
    #pragma unroll
    for (int m=0;m<4;++m)
      #pragma unroll
      for (int n=0;n<4;++n)
        acc[m][n] = __builtin_amdgcn_mfma_f32_16x16x32_bf16(fa[m], fb[n], acc[m][n], 0,0,0);
  }
  __syncthreads();
  float* Tw = Te + wid*1088;
  #pragma unroll
  for (int m=0;m<4;++m) {
    #pragma unroll
    for (int n=0;n<4;++n)
      #pragma unroll
      for (int v=0;v<4;++v)
        Tw[(kg*4+v)*68 + n*16 + r16] = acc[m][n][v];
    #pragma unroll
    for (int rr=0;rr<4;++rr) {
      int r = rr*4 + (lane>>4);
      int c4 = lane & 15;
      float4 v4 = *(const float4*)&Tw[r*68 + c4*4];
      int row = row0 + wr*64 + m*16 + r;
      *(float4*)(ypart + (size_t)row*128 + wc*64 + c4*4) = v4;
    }
  }
}

// ---------------- GroupNorm stats + partial-sum -> ysum ----------------
__global__ __launch_bounds__(256) void k_gnstat(const float* __restrict__ yp,
    float* __restrict__ ysum, float* __restrict__ part)
{
  const int bg = blockIdx.x >> 4;
  const int blk = blockIdx.x & 15;
  const int b = bg >> 2, g = bg & 3;
  const size_t P = (size_t)ROWS*128;
  float s=0.f, q=0.f;
  #pragma unroll
  for (int i=0;i<8;++i) {
    int e4 = blk*2048 + threadIdx.x + i*256;
    int l = e4 >> 3, c4 = e4 & 7;
    size_t base = (size_t)(b*Ln + l)*128 + g*32 + c4*4;
    float4 v0 = *(const float4*)(yp + base);
    float4 v1 = *(const float4*)(yp + P + base);
    float4 v2 = *(const float4*)(yp + 2*P + base);
    float4 v3 = *(const float4*)(yp + 3*P + base);
    float4 v;
    v.x = v0.x+v1.x+v2.x+v3.x;
    v.y = v0.y+v1.y+v2.y+v3.y;
    v.z = v0.z+v1.z+v2.z+v3.z;
    v.w = v0.w+v1.w+v2.w+v3.w;
    *(float4*)(ysum + base) = v;
    s += v.x+v.y+v.z+v.w;
    q = fmaf(v.x,v.x, fmaf(v.y,v.y, fmaf(v.z,v.z, fmaf(v.w,v.w, q))));
  }
  __shared__ float rs[256], rq[256];
  rs[threadIdx.x]=s; rq[threadIdx.x]=q;
  __syncthreads();
  for (int off=128; off>0; off>>=1) {
    if (threadIdx.x < off) { rs[threadIdx.x]+=rs[threadIdx.x+off]; rq[threadIdx.x]+=rq[threadIdx.x+off]; }
    __syncthreads();
  }
  if (threadIdx.x==0) { part[blockIdx.x*2]=rs[0]; part[blockIdx.x*2+1]=rq[0]; }
}

__global__ void k_gnred(const float* __restrict__ part, float* __restrict__ mr)
{
  int t = threadIdx.x;
  if (t < 16) {
    float s=0.f,q=0.f;
    for (int k=0;k<16;++k){ s+=part[(t*16+k)*2]; q+=part[(t*16+k)*2+1]; }
    const float inv = 1.f/131072.f;
    float mean = s*inv;
    float var = fmaf(-mean, mean, q*inv);
    mr[t*2] = mean;
    mr[t*2+1] = rsqrtf(var + 1e-5f);
  }
}

// ---------------- GN apply + silu + residual ----------------
__global__ __launch_bounds__(256) void k_gnapply(const float* __restrict__ ysum,
    const float* __restrict__ mr, const float* __restrict__ gamma, const float* __restrict__ beta,
    const float* __restrict__ x, float* __restrict__ out)
{
  const int b = blockIdx.x >> 6;
  const int l0 = (blockIdx.x & 63) * 64;
  __shared__ float T[64][132];
  const int tid = threadIdx.x;
  #pragma unroll
  for (int j=0;j<8;++j) {
    int f = tid + j*256;
    int l = f >> 5, c4 = f & 31;
    *(float4*)&T[l][c4*4] = *(const float4*)(ysum + (size_t)(b*Ln + l0 + l)*128 + c4*4);
  }
  __syncthreads();
  #pragma unroll
  for (int j=0;j<8;++j) {
    int f = tid + j*256;
    int c = f >> 4, lv = f & 15;
    int bg = b*4 + (c>>5);
    float mean = mr[bg*2];
    float rstd = mr[bg*2+1];
    float gam = gamma[c], bet = beta[c];
    size_t base = (size_t)(b*Cn + c)*Ln + l0 + lv*4;
    float4 xv = *(const float4*)(x + base);
    float4 r;
    r.x = siluf(fmaf((T[lv*4+0][c]-mean)*rstd, gam, bet)) + xv.x;
    r.y = siluf(fmaf((T[lv*4+1][c]-mean)*rstd, gam, bet)) + xv.y;
    r.z = siluf(fmaf((T[lv*4+2][c]-mean)*rstd, gam, bet)) + xv.z;
    r.w = siluf(fmaf((T[lv*4+3][c]-mean)*rstd, gam, bet)) + xv.w;
    *(float4*)(out + base) = r;
  }
}

extern "C" void kernel_launch(void* const* d_in, const int* in_sizes, int n_in,
                              void* d_out, int out_size, void* d_ws, size_t ws_size,
                              hipStream_t stream) {
  const float* x      = (const float*)d_in[0];
  const float* W_in_f = (const float*)d_in[1];
  const float* cw_f   = (const float*)d_in[2];
  const float* cb_f   = (const float*)d_in[3];
  const float* Wx_f   = (const float*)d_in[4];
  const float* Wdt_f  = (const float*)d_in[5];
  const float* bdt_f  = (const float*)d_in[6];
  const float* Al_f   = (const float*)d_in[7];
  const float* D_f    = (const float*)d_in[8];
  const float* Wo_f   = (const float*)d_in[9];
  const float* W_in_b = (const float*)d_in[10];
  const float* cw_b   = (const float*)d_in[11];
  const float* cb_b   = (const float*)d_in[12];
  const float* Wx_b   = (const float*)d_in[13];
  const float* Wdt_b  = (const float*)d_in[14];
  const float* bdt_b  = (const float*)d_in[15];
  const float* Al_b   = (const float*)d_in[16];
  const float* D_b    = (const float*)d_in[17];
  const float* Wo_b   = (const float*)d_in[18];
  const float* gamma  = (const float*)d_in[19];
  const float* beta   = (const float*)d_in[20];
  float* out = (float*)d_out;

  float* w = (float*)d_ws;
  size_t o = 0;
  float* xp0 = w + o; o += (size_t)ROWS*256;
  float* xp1 = w + o; o += (size_t)ROWS*256;
  unsigned short* xc0 = (unsigned short*)(w + o); o += (size_t)ROWS*128;
  unsigned short* xc1 = (unsigned short*)(w + o); o += (size_t)ROWS*128;
  unsigned short* zb0 = (unsigned short*)(w + o); o += (size_t)ROWS*128;
  unsigned short* zb1 = (unsigned short*)(w + o); o += (size_t)ROWS*128;
  unsigned short* yg0 = (unsigned short*)(w + o); o += (size_t)ROWS*128;
  unsigned short* yg1 = (unsigned short*)(w + o); o += (size_t)ROWS*128;
  float* xdb0 = w + o; o += (size_t)ROWS*40;
  float* xdb1 = w + o; o += (size_t)ROWS*40;
  float* sdt0 = w + o; o += (size_t)Bn*NCn*256;
  float* sdt1 = w + o; o += (size_t)Bn*NCn*256;
  float* hk0  = w + o; o += (size_t)Bn*NCn*16*256;
  float* hk1  = w + o; o += (size_t)Bn*NCn*16*256;
  float* part = w + o; o += 512;
  float* mr   = w + o; o += 32;
  float* yp   = xp0;
  float* ysum = xdb0;
  if (ws_size < o*sizeof(float)) return;

  k_g1<<<dim3(ROWS/128, 4, 2), 256, 0, stream>>>(x, W_in_f, W_in_b, xp0, xp1, zb0, zb1);
  k_conv<<<dim3(1024, 2), 256, 0, stream>>>(xp0, xp1, cw_f, cw_b, cb_f, cb_b, xc0, xc1);
  k_g2<<<dim3(ROWS/128, 1, 2), 256, 0, stream>>>(xc0, xc1, Wx_f, Wx_b, xdb0, xdb1);
  k_pass1<<<dim3(Bn*NCn*2, 2), 128, 0, stream>>>(xdb0, xdb1, xc0, xc1, Wdt_f, Wdt_b,
                                                 bdt_f, bdt_b, Al_f, Al_b, sdt0, sdt1, hk0, hk1);
  k_pass2<<<dim3(64, 2), 256, 0, stream>>>(Al_f, Al_b, sdt0, sdt1, hk0, hk1);
  k_pass3<<<dim3(Bn*NCn*2, 2), 128, 0, stream>>>(xdb0, xdb1, xc0, xc1, Wdt_f, Wdt_b,
                                                 bdt_f, bdt_b, Al_f, Al_b, D_f, D_b,
                                                 hk0, hk1, zb0, zb1, yg0, yg1);
  k_gout<<<dim3(ROWS/128, 2, 2), 256, 0, stream>>>(yg0, yg1, Wo_f, Wo_b, yp);
  k_gnstat<<<dim3(256), 256, 0, stream>>>(yp, ysum, part);
  k_gnred<<<dim3(1), 64, 0, stream>>>(part, mr);
  k_gnapply<<<dim3(256), 256, 0, stream>>>(ysum, mr, gamma, beta, x, out);
}

// Round 8
// 153.978 us; speedup vs baseline: 1.4841x; 1.1931x over previous
//
#include <hip/hip_runtime.h>

#define Bn 4
#define Ln 4096
#define Cn 128
#define DIn 256
#define NCn 128
#define LCn 32
#define ROWS (Bn*Ln)

typedef short s8v __attribute__((ext_vector_type(8)));
typedef short s4v __attribute__((ext_vector_type(4)));
typedef unsigned short u8v __attribute__((ext_vector_type(8)));
typedef unsigned short u4v __attribute__((ext_vector_type(4)));
typedef float f4v __attribute__((ext_vector_type(4)));

__device__ __forceinline__ float siluf(float x){ return x / (1.f + __expf(-x)); }
__device__ __forceinline__ unsigned short bfr(float f){
  uint u = __float_as_uint(f);
  return (unsigned short)((u + 0x7fffu + ((u>>16)&1u)) >> 16);
}
__device__ __forceinline__ float bf2f(unsigned short u){ return __uint_as_float(((uint)u)<<16); }

// dt = softplus(r); w = exp(-dt) = sigmoid(-r). 3 trans ops total.
__device__ __forceinline__ void sp_w(float r, float& dtv, float& w){
  float e = __expf(-fabsf(r));
  float rc = 1.f / (1.f + e);
  dtv = fmaxf(r, 0.f) + __logf(1.f + e);
  w = (r > 0.f) ? e * rc : rc;
}

// LDS tile layout (Nx32 bf16 tile): subtiles [16r][32k]; granule (8 shorts)
// XOR-swizzled by ((r>>1)&3) -> wave s8v reads are ~2-way bank-aliased (free, m136).
__device__ __forceinline__ int tile_off(int r, int gran, int ghalf){
  return ((r>>4)<<9) + ((r&15)<<5) + (((gran ^ ((r>>1)&3)))<<3) + ghalf;
}

#define SMEMB 18432

// ---------------- G1 (bf16 MFMA): xz = (dir? rev xs : xs) @ W_in ----------------
__global__ __launch_bounds__(256) void k_g1(const float* __restrict__ x,
    const float* __restrict__ Wf, const float* __restrict__ Wb,
    float* __restrict__ xpf, float* __restrict__ xpb,
    unsigned short* __restrict__ zbf, unsigned short* __restrict__ zbb)
{
  const int dir = blockIdx.z;
  const float* __restrict__ W = dir ? Wb : Wf;
  float* __restrict__ xp = dir ? xpb : xpf;
  unsigned short* __restrict__ zb = dir ? zbb : zbf;
  const int row0 = blockIdx.x * 128;
  const int n0 = blockIdx.y;
  const int b = row0 >> 12;
  const int t0 = row0 & (Ln-1);
  const float* __restrict__ xb = x + (size_t)b * Cn * Ln;

  __shared__ __align__(16) char smem[SMEMB];
  short* Ast = (short*)smem;
  short* Bst = (short*)smem + 8*512;
  float* Te  = (float*)smem;

  const int tid = threadIdx.x;
  const int lane = tid & 63;
  const int wid = tid >> 6;
  const int wr = wid >> 1, wc = wid & 1;
  const int r16 = lane & 15, kg = lane >> 4;

  const int q = tid & 31, kq = tid >> 5;
  const int kbase = 4*kq;
  const int g_true = kq >> 1;
  const int ghalf = (kq & 1) * 4;

  f4v acc[4][4];
  #pragma unroll
  for (int i=0;i<4;++i)
    #pragma unroll
    for (int j=0;j<4;++j) acc[i][j] = (f4v){0.f,0.f,0.f,0.f};

  float4 va[4], vb[4];
  {
    #pragma unroll
    for (int kk=0;kk<4;++kk) {
      va[kk] = (dir==0)
        ? *(const float4*)(xb + (size_t)(kbase+kk)*Ln + t0 + 4*q)
        : *(const float4*)(xb + (size_t)(kbase+kk)*Ln + (Ln-4 - t0 - 4*q));
      vb[kk] = *(const float4*)(W + (size_t)(kbase+kk)*512 + n0*128 + 4*q);
    }
  }
  for (int ks=0; ks<4; ++ks) {
    if (ks) __syncthreads();
    #pragma unroll
    for (int e=0;e<4;++e) {
      int r = 4*q + e;
      int off = tile_off(r, g_true, ghalf);
      int c = dir ? (3-e) : e;
      s4v hv;
      #pragma unroll
      for (int kk=0;kk<4;++kk) hv[kk] = (short)bfr(((const float*)&va[kk])[c]);
      *(s4v*)&Ast[off] = hv;
    }
    #pragma unroll
    for (int e=0;e<4;++e) {
      int r = 4*q + e;
      int off = tile_off(r, g_true, ghalf);
      s4v hv;
      #pragma unroll
      for (int kk=0;kk<4;++kk) hv[kk] = (short)bfr(((const float*)&vb[kk])[e]);
      *(s4v*)&Bst[off] = hv;
    }
    __syncthreads();
    if (ks < 3) {
      const int k0n = (ks+1)*32;
      #pragma unroll
      for (int kk=0;kk<4;++kk) {
        va[kk] = (dir==0)
          ? *(const float4*)(xb + (size_t)(k0n+kbase+kk)*Ln + t0 + 4*q)
          : *(const float4*)(xb + (size_t)(k0n+kbase+kk)*Ln + (Ln-4 - t0 - 4*q));
        vb[kk] = *(const float4*)(W + (size_t)(k0n+kbase+kk)*512 + n0*128 + 4*q);
      }
    }
    const int gsh = ((kg ^ ((r16>>1)&3)) << 3);
    s8v fa[4], fb[4];
    #pragma unroll
    for (int m=0;m<4;++m) fa[m] = *(const s8v*)&Ast[(wr*4+m)*512 + r16*32 + gsh];
    #pragma unroll
    for (int n=0;n<4;++n) fb[n] = *(const s8v*)&Bst[(wc*4+n)*512 + r16*32 + gsh];
    #pragma unroll
    for (int m=0;m<4;++m)
      #pragma unroll
      for (int n=0;n<4;++n)
        acc[m][n] = __builtin_amdgcn_mfma_f32_16x16x32_bf16(fa[m], fb[n], acc[m][n], 0,0,0);
  }
  __syncthreads();
  float* Tw = Te + wid*1088;
  #pragma unroll
  for (int m=0;m<4;++m) {
    #pragma unroll
    for (int n=0;n<4;++n)
      #pragma unroll
      for (int v=0;v<4;++v)
        Tw[(kg*4+v)*68 + n*16 + r16] = acc[m][n][v];
    #pragma unroll
    for (int rr=0;rr<4;++rr) {
      int r = rr*4 + (lane>>4);
      int c4 = lane & 15;
      float4 v4 = *(const float4*)&Tw[r*68 + c4*4];
      int row = row0 + wr*64 + m*16 + r;
      int colL = wc*64 + c4*4;
      if (n0 < 2) {
        *(float4*)(xp + (size_t)row*256 + n0*128 + colL) = v4;
      } else {
        u4v u; u[0]=bfr(v4.x); u[1]=bfr(v4.y); u[2]=bfr(v4.z); u[3]=bfr(v4.w);
        *(u4v*)(zb + (size_t)row*256 + (n0-2)*128 + colL) = u;
      }
    }
  }
}

// ---------------- conv: xc = silu(conv) -> bf16 ----------------
__global__ __launch_bounds__(256) void k_conv(
    const float* __restrict__ xpf, const float* __restrict__ xpb,
    const float* __restrict__ cwf, const float* __restrict__ cwb,
    const float* __restrict__ cbf, const float* __restrict__ cbb,
    unsigned short* __restrict__ xcf, unsigned short* __restrict__ xcb)
{
  const int dir = blockIdx.y;
  const float* __restrict__ xpd = dir ? xpb : xpf;
  const float* __restrict__ cw = dir ? cwb : cwf;
  const float* __restrict__ cb = dir ? cbb : cbf;
  unsigned short* __restrict__ xc = dir ? xcb : xcf;
  const int n4 = ROWS * 64;
  for (int idx4 = blockIdx.x*256 + threadIdx.x; idx4 < n4; idx4 += gridDim.x*256) {
    int row = idx4 >> 6;
    int d0 = (idx4 & 63) * 4;
    float4 cur = *(const float4*)(xpd + (size_t)row*256 + d0);
    float4 prev = make_float4(0.f,0.f,0.f,0.f);
    if (row & (Ln-1)) prev = *(const float4*)(xpd + (size_t)(row-1)*256 + d0);
    float4 cwA = *(const float4*)(cw + d0*2);
    float4 cwB = *(const float4*)(cw + d0*2 + 4);
    float4 cb4 = *(const float4*)(cb + d0);
    u4v r;
    r[0] = bfr(siluf(fmaf(prev.x,cwA.x, fmaf(cur.x,cwA.y, cb4.x))));
    r[1] = bfr(siluf(fmaf(prev.y,cwA.z, fmaf(cur.y,cwA.w, cb4.y))));
    r[2] = bfr(siluf(fmaf(prev.z,cwB.x, fmaf(cur.z,cwB.y, cb4.z))));
    r[3] = bfr(siluf(fmaf(prev.w,cwB.z, fmaf(cur.w,cwB.w, cb4.w))));
    *(u4v*)(xc + (size_t)row*256 + d0) = r;
  }
}

// ---------------- G2 (bf16 MFMA): xdb = xc @ W_x  (M=16384 K=256 N=40 pad 64) ----------------
// 64-row tiles, 512 blocks, 4 waves 2x2 (each 32x32, 2x2 fragments).
__global__ __launch_bounds__(256) void k_g2(
    const unsigned short* __restrict__ xcf, const unsigned short* __restrict__ xcb,
    const float* __restrict__ Wxf, const float* __restrict__ Wxb,
    float* __restrict__ xdbf, float* __restrict__ xdbb)
{
  const int dir = blockIdx.z;
  const unsigned short* __restrict__ xc = dir ? xcb : xcf;
  const float* __restrict__ Wx = dir ? Wxb : Wxf;
  float* __restrict__ xdb = dir ? xdbb : xdbf;
  const int row0 = blockIdx.x * 64;

  __shared__ __align__(16) short Ast[4*512];
  __shared__ __align__(16) short Bst[4*512];

  const int tid = threadIdx.x;
  const int lane = tid & 63;
  const int wid = tid >> 6;
  const int wr = wid >> 1, wc = wid & 1;
  const int r16 = lane & 15, kg = lane >> 4;
  const int ar = tid >> 2, ag = tid & 3;     // A: row, granule
  const int bn = tid & 63, bg = tid >> 6;    // B: n-row, granule

  f4v acc[2][2];
  #pragma unroll
  for (int i=0;i<2;++i)
    #pragma unroll
    for (int j=0;j<2;++j) acc[i][j] = (f4v){0.f,0.f,0.f,0.f};

  for (int ks=0; ks<8; ++ks) {
    const int k0 = ks*32;
    if (ks) __syncthreads();
    {
      u8v u = *(const u8v*)(xc + (size_t)(row0+ar)*256 + k0 + ag*8);
      *(u8v*)&Ast[tile_off(ar, ag, 0)] = u;
    }
    {
      s8v hv;
      #pragma unroll
      for (int i=0;i<8;++i) {
        int k = k0 + bg*8 + i;
        float f = (bn < 40) ? Wx[(size_t)k*40 + bn] : 0.f;
        hv[i] = (short)bfr(f);
      }
      *(s8v*)&Bst[tile_off(bn, bg, 0)] = hv;
    }
    __syncthreads();
    const int gsh = ((kg ^ ((r16>>1)&3)) << 3);
    s8v fa[2], fb[2];
    #pragma unroll
    for (int m=0;m<2;++m) fa[m] = *(const s8v*)&Ast[(wr*2+m)*512 + r16*32 + gsh];
    #pragma unroll
    for (int n=0;n<2;++n) fb[n] = *(const s8v*)&Bst[(wc*2+n)*512 + r16*32 + gsh];
    #pragma unroll
    for (int m=0;m<2;++m)
      #pragma unroll
      for (int n=0;n<2;++n)
        acc[m][n] = __builtin_amdgcn_mfma_f32_16x16x32_bf16(fa[m], fb[n], acc[m][n], 0,0,0);
  }
  #pragma unroll
  for (int m=0;m<2;++m)
    #pragma unroll
    for (int n=0;n<2;++n) {
      int col = wc*32 + n*16 + r16;
      if (col < 40) {
        #pragma unroll
        for (int v=0;v<4;++v) {
          int row = row0 + wr*32 + m*16 + kg*4 + v;
          xdb[(size_t)row*40 + col] = acc[m][n][v];
        }
      }
    }
}

// ---------------- pass1: per-chunk local scan; b128 S reads; dual chains ----------------
__global__ __launch_bounds__(128,4) void k_pass1(
    const float* __restrict__ xdbf, const float* __restrict__ xdbb,
    const unsigned short* __restrict__ xcf, const unsigned short* __restrict__ xcb,
    const float* __restrict__ Wdtf, const float* __restrict__ Wdtb,
    const float* __restrict__ bdtf, const float* __restrict__ bdtb,
    const float* __restrict__ Alf, const float* __restrict__ Alb,
    float* __restrict__ sdtf, float* __restrict__ sdtb,
    float* __restrict__ hkf, float* __restrict__ hkb)
{
  const int dir = blockIdx.y;
  const float* __restrict__ xdb = dir ? xdbb : xdbf;
  const unsigned short* __restrict__ xc = dir ? xcb : xcf;
  const float* __restrict__ Wdt = dir ? Wdtb : Wdtf;
  const float* __restrict__ bdt = dir ? bdtb : bdtf;
  const float* __restrict__ Al  = dir ? Alb  : Alf;
  float* __restrict__ sdt = dir ? sdtb : sdtf;
  float* __restrict__ hk  = dir ? hkb  : hkf;
  const int dh = blockIdx.x & 1;
  const int cc = blockIdx.x >> 1;
  const int b = cc >> 7, c = cc & 127;
  const int t0 = c * LCn;
  __shared__ float S[LCn*32];   // [t][0..7]=dt_r [8..23]=B, stride 32
  const int tid = threadIdx.x;
  #pragma unroll
  for (int j=0;j<6;++j) {
    int idx = tid + j*128;
    int t = idx/24, jj = idx - t*24;
    S[t*32 + jj] = xdb[(size_t)(b*Ln + t0 + t)*40 + jj];
  }
  const int d = dh*128 + tid;
  float Areg[16];
  bool st = true;
  #pragma unroll
  for (int s=0;s<16;++s) {
    Areg[s] = -__expf(Al[d*16+s]);
    st = st && (fabsf(Areg[s] + (float)(s+1)) <= 3e-5f*(float)(s+1));
  }
  float wdt[8];
  #pragma unroll
  for (int j=0;j<8;++j) wdt[j] = Wdt[j*256+d];
  const float bd = bdt[d];
  float h[16];
  #pragma unroll
  for (int s=0;s<16;++s) h[s]=0.f;
  float sacc = 0.f;
  __syncthreads();
  if (st) {
    #pragma unroll 2
    for (int t=0;t<LCn;++t) {
      float4 sA = *(const float4*)&S[t*32];
      float4 sB = *(const float4*)&S[t*32+4];
      float rr = bd;
      rr = fmaf(sA.x,wdt[0], fmaf(sA.y,wdt[1], fmaf(sA.z,wdt[2], fmaf(sA.w,wdt[3], rr))));
      rr = fmaf(sB.x,wdt[4], fmaf(sB.y,wdt[5], fmaf(sB.z,wdt[6], fmaf(sB.w,wdt[7], rr))));
      float dtv, wv;
      sp_w(rr, dtv, wv);
      float bq[16];
      #pragma unroll
      for (int i=0;i<4;++i) *(float4*)&bq[4*i] = *(const float4*)&S[t*32 + 8 + 4*i];
      float xv = bf2f(xc[(size_t)(b*Ln + t0 + t)*256 + d]);
      float u = dtv * xv;
      sacc += dtv;
      float w2 = wv*wv, w4 = w2*w2;
      float wpa = wv, wpb = w4*w4*wv;   // w^9
      #pragma unroll
      for (int s=0;s<8;++s) {
        h[s]   = fmaf(h[s],   wpa, u*bq[s]);
        h[s+8] = fmaf(h[s+8], wpb, u*bq[s+8]);
        wpa *= wv; wpb *= wv;
      }
    }
  } else {
    #pragma unroll 2
    for (int t=0;t<LCn;++t) {
      float4 sA = *(const float4*)&S[t*32];
      float4 sB = *(const float4*)&S[t*32+4];
      float rr = bd;
      rr = fmaf(sA.x,wdt[0], fmaf(sA.y,wdt[1], fmaf(sA.z,wdt[2], fmaf(sA.w,wdt[3], rr))));
      rr = fmaf(sB.x,wdt[4], fmaf(sB.y,wdt[5], fmaf(sB.z,wdt[6], fmaf(sB.w,wdt[7], rr))));
      float dtv, wv;
      sp_w(rr, dtv, wv);
      float bq[16];
      #pragma unroll
      for (int i=0;i<4;++i) *(float4*)&bq[4*i] = *(const float4*)&S[t*32 + 8 + 4*i];
      float xv = bf2f(xc[(size_t)(b*Ln + t0 + t)*256 + d]);
      float u = dtv * xv;
      sacc += dtv;
      #pragma unroll
      for (int s=0;s<16;++s)
        h[s] = fmaf(h[s], __expf(dtv*Areg[s]), u*bq[s]);
    }
  }
  sdt[(size_t)(b*NCn + c)*256 + d] = sacc;
  #pragma unroll
  for (int s=0;s<16;++s)
    hk[(size_t)((b*NCn + c)*16 + s)*256 + d] = h[s];
}

// ---------------- pass2: inter-chunk recurrence, explicit prefetch ----------------
__global__ __launch_bounds__(256) void k_pass2(
    const float* __restrict__ Alf, const float* __restrict__ Alb,
    const float* __restrict__ sdtf, const float* __restrict__ sdtb,
    float* __restrict__ hkf, float* __restrict__ hkb)
{
  const int dir = blockIdx.y;
  const float* __restrict__ Al  = dir ? Alb : Alf;
  const float* __restrict__ sdt = dir ? sdtb : sdtf;
  float* __restrict__ hk = dir ? hkb : hkf;
  int g = blockIdx.x*256 + threadIdx.x;
  int d = g & 255, s = (g >> 8) & 15, b = g >> 12;
  float Ad = -__expf(Al[d*16+s]);
  float h = 0.f;
  float sd_n = sdt[(size_t)(b*NCn)*256 + d];
  size_t hi_n = (size_t)((b*NCn)*16 + s)*256 + d;
  float he_n = hk[hi_n];
  for (int c=0;c<NCn;++c) {
    float sd = sd_n, he = he_n;
    size_t hi = hi_n;
    if (c+1 < NCn) {
      int bc = b*NCn + c + 1;
      sd_n = sdt[(size_t)bc*256 + d];
      hi_n = (size_t)(bc*16 + s)*256 + d;
      he_n = hk[hi_n];
    }
    hk[hi] = h;
    h = fmaf(__expf(Ad*sd), h, he);
  }
}

// ---------------- pass3: replay; b128 S reads; dual chains; gate silu(z) -> yg bf16 ----------
__global__ __launch_bounds__(128,4) void k_pass3(
    const float* __restrict__ xdbf, const float* __restrict__ xdbb,
    const unsigned short* __restrict__ xcf, const unsigned short* __restrict__ xcb,
    const float* __restrict__ Wdtf, const float* __restrict__ Wdtb,
    const float* __restrict__ bdtf, const float* __restrict__ bdtb,
    const float* __restrict__ Alf, const float* __restrict__ Alb,
    const float* __restrict__ Dvf, const float* __restrict__ Dvb,
    const float* __restrict__ hkf, const float* __restrict__ hkb,
    const unsigned short* __restrict__ zbf, const unsigned short* __restrict__ zbb,
    unsigned short* __restrict__ ygf, unsigned short* __restrict__ ygb)
{
  const int dir = blockIdx.y;
  const float* __restrict__ xdb = dir ? xdbb : xdbf;
  const unsigned short* __restrict__ xc = dir ? xcb : xcf;
  const float* __restrict__ Wdt = dir ? Wdtb : Wdtf;
  const float* __restrict__ bdt = dir ? bdtb : bdtf;
  const float* __restrict__ Al  = dir ? Alb  : Alf;
  const float* __restrict__ Dv  = dir ? Dvb  : Dvf;
  const float* __restrict__ hk  = dir ? hkb  : hkf;
  const unsigned short* __restrict__ zbd = dir ? zbb : zbf;
  unsigned short* __restrict__ yg = dir ? ygb : ygf;
  const int dh = blockIdx.x & 1;
  const int cc = blockIdx.x >> 1;
  const int b = cc >> 7, c = cc & 127;
  const int t0 = c * LCn;
  __shared__ float S[LCn*48];   // [t][0..7]=dt_r [8..23]=B [24..39]=C, stride 48
  const int tid = threadIdx.x;
  #pragma unroll
  for (int j=0;j<10;++j) {
    int idx = tid + j*128;
    int t = idx/40, jj = idx - t*40;
    S[t*48 + jj] = xdb[(size_t)(b*Ln + t0 + t)*40 + jj];
  }
  const int d = dh*128 + tid;
  float Areg[16];
  bool st = true;
  #pragma unroll
  for (int s=0;s<16;++s) {
    Areg[s] = -__expf(Al[d*16+s]);
    st = st && (fabsf(Areg[s] + (float)(s+1)) <= 3e-5f*(float)(s+1));
  }
  float wdt[8];
  #pragma unroll
  for (int j=0;j<8;++j) wdt[j] = Wdt[j*256+d];
  const float bd = bdt[d];
  const float Dd = Dv[d];
  float h[16];
  #pragma unroll
  for (int s=0;s<16;++s) h[s] = hk[(size_t)((b*NCn + c)*16 + s)*256 + d];
  __syncthreads();
  if (st) {
    #pragma unroll 2
    for (int t=0;t<LCn;++t) {
      float4 sA = *(const float4*)&S[t*48];
      float4 sB = *(const float4*)&S[t*48+4];
      float rr = bd;
      rr = fmaf(sA.x,wdt[0], fmaf(sA.y,wdt[1], fmaf(sA.z,wdt[2], fmaf(sA.w,wdt[3], rr))));
      rr = fmaf(sB.x,wdt[4], fmaf(sB.y,wdt[5], fmaf(sB.z,wdt[6], fmaf(sB.w,wdt[7], rr))));
      float dtv, wv;
      sp_w(rr, dtv, wv);
      float bq[16], cq[16];
      #pragma unroll
      for (int i=0;i<4;++i) {
        *(float4*)&bq[4*i] = *(const float4*)&S[t*48 + 8 + 4*i];
        *(float4*)&cq[4*i] = *(const float4*)&S[t*48 + 24 + 4*i];
      }
      size_t rowi = (size_t)(b*Ln + t0 + t);
      float xv = bf2f(xc[rowi*256 + d]);
      float u = dtv * xv;
      float w2 = wv*wv, w4 = w2*w2;
      float wpa = wv, wpb = w4*w4*wv;
      float yA = 0.f, yB = 0.f;
      #pragma unroll
      for (int s=0;s<8;++s) {
        h[s]   = fmaf(h[s],   wpa, u*bq[s]);
        yA = fmaf(h[s], cq[s], yA);
        h[s+8] = fmaf(h[s+8], wpb, u*bq[s+8]);
        yB = fmaf(h[s+8], cq[s+8], yB);
        wpa *= wv; wpb *= wv;
      }
      float y = fmaf(Dd, xv, yA + yB);
      float zv = bf2f(zbd[rowi*256 + d]);
      yg[rowi*256 + d] = bfr(y * siluf(zv));
    }
  } else {
    #pragma unroll 2
    for (int t=0;t<LCn;++t) {
      float4 sA = *(const float4*)&S[t*48];
      float4 sB = *(const float4*)&S[t*48+4];
      float rr = bd;
      rr = fmaf(sA.x,wdt[0], fmaf(sA.y,wdt[1], fmaf(sA.z,wdt[2], fmaf(sA.w,wdt[3], rr))));
      rr = fmaf(sB.x,wdt[4], fmaf(sB.y,wdt[5], fmaf(sB.z,wdt[6], fmaf(sB.w,wdt[7], rr))));
      float dtv, wv;
      sp_w(rr, dtv, wv);
      float bq[16], cq[16];
      #pragma unroll
      for (int i=0;i<4;++i) {
        *(float4*)&bq[4*i] = *(const float4*)&S[t*48 + 8 + 4*i];
        *(float4*)&cq[4*i] = *(const float4*)&S[t*48 + 24 + 4*i];
      }
      size_t rowi = (size_t)(b*Ln + t0 + t);
      float xv = bf2f(xc[rowi*256 + d]);
      float u = dtv * xv;
      float y = 0.f;
      #pragma unroll
      for (int s=0;s<16;++s) {
        h[s] = fmaf(h[s], __expf(dtv*Areg[s]), u*bq[s]);
        y = fmaf(h[s], cq[s], y);
      }
      y = fmaf(Dd, xv, y);
      float zv = bf2f(zbd[rowi*256 + d]);
      yg[rowi*256 + d] = bfr(y * siluf(zv));
    }
  }
}

// ---------------- Gout (bf16 MFMA): ypart[dir*2+khalf] = yg[dir] @ W_out[dir] ----------------
__global__ __launch_bounds__(256) void k_gout(
    const unsigned short* __restrict__ ygf, const unsigned short* __restrict__ ygb,
    const float* __restrict__ Wof, const float* __restrict__ Wob,
    float* __restrict__ yp)
{
  const int row0 = blockIdx.x * 128;
  const int khalf = blockIdx.y;
  const int dir = blockIdx.z;
  const unsigned short* __restrict__ ygd = dir ? ygb : ygf;
  const float* __restrict__ Wod = dir ? Wob : Wof;
  float* __restrict__ ypart = yp + (size_t)(dir*2 + khalf) * ROWS * 128;
  const int b = row0 >> 12;
  const int l0 = row0 & (Ln-1);

  __shared__ __align__(16) char smem[SMEMB];
  short* Ast = (short*)smem;
  short* Bst = (short*)smem + 8*512;
  float* Te  = (float*)smem;

  const int tid = threadIdx.x;
  const int lane = tid & 63;
  const int wid = tid >> 6;
  const int wr = wid >> 1, wc = wid & 1;
  const int r16 = lane & 15, kg = lane >> 4;

  const int ar = tid >> 1, kh = tid & 1;
  const int q = tid & 31, kq = tid >> 5;
  const int kbase = 4*kq;
  const int g_true = kq >> 1;
  const int ghalf = (kq & 1) * 4;

  f4v acc[4][4];
  #pragma unroll
  for (int i=0;i<4;++i)
    #pragma unroll
    for (int j=0;j<4;++j) acc[i][j] = (f4v){0.f,0.f,0.f,0.f};

  for (int ks=0; ks<4; ++ks) {
    const int kk0 = khalf*128 + ks*32;
    if (ks) __syncthreads();
    {
      int rl = l0 + ar;
      size_t srow = (size_t)b*Ln + (dir ? (Ln-1-rl) : rl);
      const unsigned short* s = ygd + srow*256 + kk0 + kh*16;
      u8v u0 = *(const u8v*)(s);
      u8v u1 = *(const u8v*)(s + 8);
      int o0 = tile_off(ar, 2*kh,   0);
      int o1 = tile_off(ar, 2*kh+1, 0);
      *(u8v*)&Ast[o0] = u0;
      *(u8v*)&Ast[o1] = u1;
    }
    {
      float4 vb[4];
      #pragma unroll
      for (int kk=0;kk<4;++kk)
        vb[kk] = *(const float4*)(Wod + (size_t)(kk0+kbase+kk)*128 + 4*q);
      #pragma unroll
      for (int e=0;e<4;++e) {
        int r = 4*q + e;
        int off = tile_off(r, g_true, ghalf);
        s4v hv;
        #pragma unroll
        for (int kk=0;kk<4;++kk) hv[kk] = (short)bfr(((const float*)&vb[kk])[e]);
        *(s4v*)&Bst[off] = hv;
      }
    }
    __syncthreads();
    const int gsh = ((kg ^ ((r16>>1)&3)) << 3);
    s8v fa[4], fb[4];
    #pragma unroll
    for (int m=0;m<4;++m) fa[m] = *(const s8v*)&Ast[(wr*4+m)*512 + r16*32 + gsh];
    #pragma unroll
    for (int n=0;n<4;++n) fb[n] = *(const s8v*)&Bst[(wc*4+n)*512 + r16*32 + gsh];
    #pragma unroll
    for (int m=0;m<4;++m)
      #pragma unroll
      for (int n=0;n<4;++n)
        acc[m][n] = __builtin_amdgcn_mfma_f32_16x16x32_bf16(fa[m], fb[n], acc[m][n], 0,0,0);
  }
  __syncthreads();
  float* Tw = Te + wid*1088;
  #pragma unroll
  for (int m=0;m<4;++m) {
    #pragma unroll
    for (int n=0;n<4;++n)
      #pragma unroll
      for (int v=0;v<4;++v)
        Tw[(kg*4+v)*68 + n*16 + r16] = acc[m][n][v];
    #pragma unroll
    for (int rr=0;rr<4;++rr) {
      int r = rr*4 + (lane>>4);
      int c4 = lane & 15;
      float4 v4 = *(const float4*)&Tw[r*68 + c4*4];
      int row = row0 + wr*64 + m*16 + r;
      *(float4*)(ypart + (size_t)row*128 + wc*64 + c4*4) = v4;
    }
  }
}

// ---------------- GroupNorm stats + partial-sum -> ysum ----------------
__global__ __launch_bounds__(256) void k_gnstat(const float* __restrict__ yp,
    float* __restrict__ ysum, float* __restrict__ part)
{
  const int bg = blockIdx.x >> 4;
  const int blk = blockIdx.x & 15;
  const int b = bg >> 2, g = bg & 3;
  const size_t P = (size_t)ROWS*128;
  float s=0.f, q=0.f;
  #pragma unroll
  for (int i=0;i<8;++i) {
    int e4 = blk*2048 + threadIdx.x + i*256;
    int l = e4 >> 3, c4 = e4 & 7;
    size_t base = (size_t)(b*Ln + l)*128 + g*32 + c4*4;
    float4 v0 = *(const float4*)(yp + base);
    float4 v1 = *(const float4*)(yp + P + base);
    float4 v2 = *(const float4*)(yp + 2*P + base);
    float4 v3 = *(const float4*)(yp + 3*P + base);
    float4 v;
    v.x = v0.x+v1.x+v2.x+v3.x;
    v.y = v0.y+v1.y+v2.y+v3.y;
    v.z = v0.z+v1.z+v2.z+v3.z;
    v.w = v0.w+v1.w+v2.w+v3.w;
    *(float4*)(ysum + base) = v;
    s += v.x+v.y+v.z+v.w;
    q = fmaf(v.x,v.x, fmaf(v.y,v.y, fmaf(v.z,v.z, fmaf(v.w,v.w, q))));
  }
  __shared__ float rs[256], rq[256];
  rs[threadIdx.x]=s; rq[threadIdx.x]=q;
  __syncthreads();
  for (int off=128; off>0; off>>=1) {
    if (threadIdx.x < off) { rs[threadIdx.x]+=rs[threadIdx.x+off]; rq[threadIdx.x]+=rq[threadIdx.x+off]; }
    __syncthreads();
  }
  if (threadIdx.x==0) { part[blockIdx.x*2]=rs[0]; part[blockIdx.x*2+1]=rq[0]; }
}

__global__ void k_gnred(const float* __restrict__ part, float* __restrict__ mr)
{
  int t = threadIdx.x;
  if (t < 16) {
    float s=0.f,q=0.f;
    for (int k=0;k<16;++k){ s+=part[(t*16+k)*2]; q+=part[(t*16+k)*2+1]; }
    const float inv = 1.f/131072.f;
    float mean = s*inv;
    float var = fmaf(-mean, mean, q*inv);
    mr[t*2] = mean;
    mr[t*2+1] = rsqrtf(var + 1e-5f);
  }
}

// ---------------- GN apply + silu + residual ----------------
__global__ __launch_bounds__(256) void k_gnapply(const float* __restrict__ ysum,
    const float* __restrict__ mr, const float* __restrict__ gamma, const float* __restrict__ beta,
    const float* __restrict__ x, float* __restrict__ out)
{
  const int b = blockIdx.x >> 6;
  const int l0 = (blockIdx.x & 63) * 64;
  __shared__ float T[64][132];
  const int tid = threadIdx.x;
  #pragma unroll
  for (int j=0;j<8;++j) {
    int f = tid + j*256;
    int l = f >> 5, c4 = f & 31;
    *(float4*)&T[l][c4*4] = *(const float4*)(ysum + (size_t)(b*Ln + l0 + l)*128 + c4*4);
  }
  __syncthreads();
  #pragma unroll
  for (int j=0;j<8;++j) {
    int f = tid + j*256;
    int c = f >> 4, lv = f & 15;
    int bg = b*4 + (c>>5);
    float mean = mr[bg*2];
    float rstd = mr[bg*2+1];
    float gam = gamma[c], bet = beta[c];
    size_t base = (size_t)(b*Cn + c)*Ln + l0 + lv*4;
    float4 xv = *(const float4*)(x + base);
    float4 r;
    r.x = siluf(fmaf((T[lv*4+0][c]-mean)*rstd, gam, bet)) + xv.x;
    r.y = siluf(fmaf((T[lv*4+1][c]-mean)*rstd, gam, bet)) + xv.y;
    r.z = siluf(fmaf((T[lv*4+2][c]-mean)*rstd, gam, bet)) + xv.z;
    r.w = siluf(fmaf((T[lv*4+3][c]-mean)*rstd, gam, bet)) + xv.w;
    *(float4*)(out + base) = r;
  }
}

extern "C" void kernel_launch(void* const* d_in, const int* in_sizes, int n_in,
                              void* d_out, int out_size, void* d_ws, size_t ws_size,
                              hipStream_t stream) {
  const float* x      = (const float*)d_in[0];
  const float* W_in_f = (const float*)d_in[1];
  const float* cw_f   = (const float*)d_in[2];
  const float* cb_f   = (const float*)d_in[3];
  const float* Wx_f   = (const float*)d_in[4];
  const float* Wdt_f  = (const float*)d_in[5];
  const float* bdt_f  = (const float*)d_in[6];
  const float* Al_f   = (const float*)d_in[7];
  const float* D_f    = (const float*)d_in[8];
  const float* Wo_f   = (const float*)d_in[9];
  const float* W_in_b = (const float*)d_in[10];
  const float* cw_b   = (const float*)d_in[11];
  const float* cb_b   = (const float*)d_in[12];
  const float* Wx_b   = (const float*)d_in[13];
  const float* Wdt_b  = (const float*)d_in[14];
  const float* bdt_b  = (const float*)d_in[15];
  const float* Al_b   = (const float*)d_in[16];
  const float* D_b    = (const float*)d_in[17];
  const float* Wo_b   = (const float*)d_in[18];
  const float* gamma  = (const float*)d_in[19];
  const float* beta   = (const float*)d_in[20];
  float* out = (float*)d_out;

  float* w = (float*)d_ws;
  size_t o = 0;
  float* xp0 = w + o; o += (size_t)ROWS*256;
  float* xp1 = w + o; o += (size_t)ROWS*256;
  unsigned short* xc0 = (unsigned short*)(w + o); o += (size_t)ROWS*128;
  unsigned short* xc1 = (unsigned short*)(w + o); o += (size_t)ROWS*128;
  unsigned short* zb0 = (unsigned short*)(w + o); o += (size_t)ROWS*128;
  unsigned short* zb1 = (unsigned short*)(w + o); o += (size_t)ROWS*128;
  unsigned short* yg0 = (unsigned short*)(w + o); o += (size_t)ROWS*128;
  unsigned short* yg1 = (unsigned short*)(w + o); o += (size_t)ROWS*128;
  float* xdb0 = w + o; o += (size_t)ROWS*40;
  float* xdb1 = w + o; o += (size_t)ROWS*40;
  float* sdt0 = w + o; o += (size_t)Bn*NCn*256;
  float* sdt1 = w + o; o += (size_t)Bn*NCn*256;
  float* hk0  = w + o; o += (size_t)Bn*NCn*16*256;
  float* hk1  = w + o; o += (size_t)Bn*NCn*16*256;
  float* part = w + o; o += 512;
  float* mr   = w + o; o += 32;
  float* yp   = xp0;
  float* ysum = xdb0;
  if (ws_size < o*sizeof(float)) return;

  k_g1<<<dim3(ROWS/128, 4, 2), 256, 0, stream>>>(x, W_in_f, W_in_b, xp0, xp1, zb0, zb1);
  k_conv<<<dim3(1024, 2), 256, 0, stream>>>(xp0, xp1, cw_f, cw_b, cb_f, cb_b, xc0, xc1);
  k_g2<<<dim3(ROWS/64, 1, 2), 256, 0, stream>>>(xc0, xc1, Wx_f, Wx_b, xdb0, xdb1);
  k_pass1<<<dim3(Bn*NCn*2, 2), 128, 0, stream>>>(xdb0, xdb1, xc0, xc1, Wdt_f, Wdt_b,
                                                 bdt_f, bdt_b, Al_f, Al_b, sdt0, sdt1, hk0, hk1);
  k_pass2<<<dim3(64, 2), 256, 0, stream>>>(Al_f, Al_b, sdt0, sdt1, hk0, hk1);
  k_pass3<<<dim3(Bn*NCn*2, 2), 128, 0, stream>>>(xdb0, xdb1, xc0, xc1, Wdt_f, Wdt_b,
                                                 bdt_f, bdt_b, Al_f, Al_b, D_f, D_b,
                                                 hk0, hk1, zb0, zb1, yg0, yg1);
  k_gout<<<dim3(ROWS/128, 2, 2), 256, 0, stream>>>(yg0, yg1, Wo_f, Wo_b, yp);
  k_gnstat<<<dim3(256), 256, 0, stream>>>(yp, ysum, part);
  k_gnred<<<dim3(1), 64, 0, stream>>>(part, mr);
  k_gnapply<<<dim3(256), 256, 0, stream>>>(ysum, mr, gamma, beta, x, out);
}

// Round 9
// 148.484 us; speedup vs baseline: 1.5390x; 1.0370x over previous
//
#include <hip/hip_runtime.h>

#define Bn 4
#define Ln 4096
#define Cn 128
#define DIn 256
#define NCn 128
#define LCn 32
#define ROWS (Bn*Ln)

typedef short s8v __attribute__((ext_vector_type(8)));
typedef short s4v __attribute__((ext_vector_type(4)));
typedef unsigned short u8v __attribute__((ext_vector_type(8)));
typedef unsigned short u4v __attribute__((ext_vector_type(4)));
typedef float f4v __attribute__((ext_vector_type(4)));
typedef float f2v __attribute__((ext_vector_type(2)));

__device__ __forceinline__ float siluf(float x){ return x / (1.f + __expf(-x)); }
__device__ __forceinline__ unsigned short bfr(float f){
  uint u = __float_as_uint(f);
  return (unsigned short)((u + 0x7fffu + ((u>>16)&1u)) >> 16);
}
__device__ __forceinline__ float bf2f(unsigned short u){ return __uint_as_float(((uint)u)<<16); }

// dt = softplus(r); w = exp(-dt) = sigmoid(-r). 3 trans ops total.
__device__ __forceinline__ void sp_w(float r, float& dtv, float& w){
  float e = __expf(-fabsf(r));
  float rc = 1.f / (1.f + e);
  dtv = fmaxf(r, 0.f) + __logf(1.f + e);
  w = (r > 0.f) ? e * rc : rc;
}

// LDS tile layout (Nx32 bf16 tile): subtiles [16r][32k]; granule (8 shorts)
// XOR-swizzled by ((r>>1)&3) -> wave s8v reads are ~2-way bank-aliased (free, m136).
__device__ __forceinline__ int tile_off(int r, int gran, int ghalf){
  return ((r>>4)<<9) + ((r&15)<<5) + (((gran ^ ((r>>1)&3)))<<3) + ghalf;
}

#define SMEMB 18432

// ---------------- G1 (bf16 MFMA): xz = (dir? rev xs : xs) @ W_in ----------------
__global__ __launch_bounds__(256) void k_g1(const float* __restrict__ x,
    const float* __restrict__ Wf, const float* __restrict__ Wb,
    float* __restrict__ xpf, float* __restrict__ xpb,
    unsigned short* __restrict__ zbf, unsigned short* __restrict__ zbb)
{
  const int dir = blockIdx.z;
  const float* __restrict__ W = dir ? Wb : Wf;
  float* __restrict__ xp = dir ? xpb : xpf;
  unsigned short* __restrict__ zb = dir ? zbb : zbf;
  const int row0 = blockIdx.x * 128;
  const int n0 = blockIdx.y;
  const int b = row0 >> 12;
  const int t0 = row0 & (Ln-1);
  const float* __restrict__ xb = x + (size_t)b * Cn * Ln;

  __shared__ __align__(16) char smem[SMEMB];
  short* Ast = (short*)smem;
  short* Bst = (short*)smem + 8*512;
  float* Te  = (float*)smem;

  const int tid = threadIdx.x;
  const int lane = tid & 63;
  const int wid = tid >> 6;
  const int wr = wid >> 1, wc = wid & 1;
  const int r16 = lane & 15, kg = lane >> 4;

  const int q = tid & 31, kq = tid >> 5;
  const int kbase = 4*kq;
  const int g_true = kq >> 1;
  const int ghalf = (kq & 1) * 4;

  f4v acc[4][4];
  #pragma unroll
  for (int i=0;i<4;++i)
    #pragma unroll
    for (int j=0;j<4;++j) acc[i][j] = (f4v){0.f,0.f,0.f,0.f};

  float4 va[4], vb[4];
  {
    #pragma unroll
    for (int kk=0;kk<4;++kk) {
      va[kk] = (dir==0)
        ? *(const float4*)(xb + (size_t)(kbase+kk)*Ln + t0 + 4*q)
        : *(const float4*)(xb + (size_t)(kbase+kk)*Ln + (Ln-4 - t0 - 4*q));
      vb[kk] = *(const float4*)(W + (size_t)(kbase+kk)*512 + n0*128 + 4*q);
    }
  }
  for (int ks=0; ks<4; ++ks) {
    if (ks) __syncthreads();
    #pragma unroll
    for (int e=0;e<4;++e) {
      int r = 4*q + e;
      int off = tile_off(r, g_true, ghalf);
      int c = dir ? (3-e) : e;
      s4v hv;
      #pragma unroll
      for (int kk=0;kk<4;++kk) hv[kk] = (short)bfr(((const float*)&va[kk])[c]);
      *(s4v*)&Ast[off] = hv;
    }
    #pragma unroll
    for (int e=0;e<4;++e) {
      int r = 4*q + e;
      int off = tile_off(r, g_true, ghalf);
      s4v hv;
      #pragma unroll
      for (int kk=0;kk<4;++kk) hv[kk] = (short)bfr(((const float*)&vb[kk])[e]);
      *(s4v*)&Bst[off] = hv;
    }
    __syncthreads();
    if (ks < 3) {
      const int k0n = (ks+1)*32;
      #pragma unroll
      for (int kk=0;kk<4;++kk) {
        va[kk] = (dir==0)
          ? *(const float4*)(xb + (size_t)(k0n+kbase+kk)*Ln + t0 + 4*q)
          : *(const float4*)(xb + (size_t)(k0n+kbase+kk)*Ln + (Ln-4 - t0 - 4*q));
        vb[kk] = *(const float4*)(W + (size_t)(k0n+kbase+kk)*512 + n0*128 + 4*q);
      }
    }
    const int gsh = ((kg ^ ((r16>>1)&3)) << 3);
    s8v fa[4], fb[4];
    #pragma unroll
    for (int m=0;m<4;++m) fa[m] = *(const s8v*)&Ast[(wr*4+m)*512 + r16*32 + gsh];
    #pragma unroll
    for (int n=0;n<4;++n) fb[n] = *(const s8v*)&Bst[(wc*4+n)*512 + r16*32 + gsh];
    #pragma unroll
    for (int m=0;m<4;++m)
      #pragma unroll
      for (int n=0;n<4;++n)
        acc[m][n] = __builtin_amdgcn_mfma_f32_16x16x32_bf16(fa[m], fb[n], acc[m][n], 0,0,0);
  }
  __syncthreads();
  float* Tw = Te + wid*1088;
  #pragma unroll
  for (int m=0;m<4;++m) {
    #pragma unroll
    for (int n=0;n<4;++n)
      #pragma unroll
      for (int v=0;v<4;++v)
        Tw[(kg*4+v)*68 + n*16 + r16] = acc[m][n][v];
    #pragma unroll
    for (int rr=0;rr<4;++rr) {
      int r = rr*4 + (lane>>4);
      int c4 = lane & 15;
      float4 v4 = *(const float4*)&Tw[r*68 + c4*4];
      int row = row0 + wr*64 + m*16 + r;
      int colL = wc*64 + c4*4;
      if (n0 < 2) {
        *(float4*)(xp + (size_t)row*256 + n0*128 + colL) = v4;
      } else {
        u4v u; u[0]=bfr(v4.x); u[1]=bfr(v4.y); u[2]=bfr(v4.z); u[3]=bfr(v4.w);
        *(u4v*)(zb + (size_t)row*256 + (n0-2)*128 + colL) = u;
      }
    }
  }
}

// ---------------- conv: xc = silu(conv) -> bf16 ----------------
__global__ __launch_bounds__(256) void k_conv(
    const float* __restrict__ xpf, const float* __restrict__ xpb,
    const float* __restrict__ cwf, const float* __restrict__ cwb,
    const float* __restrict__ cbf, const float* __restrict__ cbb,
    unsigned short* __restrict__ xcf, unsigned short* __restrict__ xcb)
{
  const int dir = blockIdx.y;
  const float* __restrict__ xpd = dir ? xpb : xpf;
  const float* __restrict__ cw = dir ? cwb : cwf;
  const float* __restrict__ cb = dir ? cbb : cbf;
  unsigned short* __restrict__ xc = dir ? xcb : xcf;
  const int n4 = ROWS * 64;
  for (int idx4 = blockIdx.x*256 + threadIdx.x; idx4 < n4; idx4 += gridDim.x*256) {
    int row = idx4 >> 6;
    int d0 = (idx4 & 63) * 4;
    float4 cur = *(const float4*)(xpd + (size_t)row*256 + d0);
    float4 prev = make_float4(0.f,0.f,0.f,0.f);
    if (row & (Ln-1)) prev = *(const float4*)(xpd + (size_t)(row-1)*256 + d0);
    float4 cwA = *(const float4*)(cw + d0*2);
    float4 cwB = *(const float4*)(cw + d0*2 + 4);
    float4 cb4 = *(const float4*)(cb + d0);
    u4v r;
    r[0] = bfr(siluf(fmaf(prev.x,cwA.x, fmaf(cur.x,cwA.y, cb4.x))));
    r[1] = bfr(siluf(fmaf(prev.y,cwA.z, fmaf(cur.y,cwA.w, cb4.y))));
    r[2] = bfr(siluf(fmaf(prev.z,cwB.x, fmaf(cur.z,cwB.y, cb4.z))));
    r[3] = bfr(siluf(fmaf(prev.w,cwB.z, fmaf(cur.w,cwB.w, cb4.w))));
    *(u4v*)(xc + (size_t)row*256 + d0) = r;
  }
}

// ---------------- G2 (bf16 MFMA): xdb = xc @ W_x ----------------
__global__ __launch_bounds__(256) void k_g2(
    const unsigned short* __restrict__ xcf, const unsigned short* __restrict__ xcb,
    const float* __restrict__ Wxf, const float* __restrict__ Wxb,
    float* __restrict__ xdbf, float* __restrict__ xdbb)
{
  const int dir = blockIdx.z;
  const unsigned short* __restrict__ xc = dir ? xcb : xcf;
  const float* __restrict__ Wx = dir ? Wxb : Wxf;
  float* __restrict__ xdb = dir ? xdbb : xdbf;
  const int row0 = blockIdx.x * 64;

  __shared__ __align__(16) short Ast[4*512];
  __shared__ __align__(16) short Bst[4*512];

  const int tid = threadIdx.x;
  const int lane = tid & 63;
  const int wid = tid >> 6;
  const int wr = wid >> 1, wc = wid & 1;
  const int r16 = lane & 15, kg = lane >> 4;
  const int ar = tid >> 2, ag = tid & 3;
  const int bn = tid & 63, bg = tid >> 6;

  f4v acc[2][2];
  #pragma unroll
  for (int i=0;i<2;++i)
    #pragma unroll
    for (int j=0;j<2;++j) acc[i][j] = (f4v){0.f,0.f,0.f,0.f};

  for (int ks=0; ks<8; ++ks) {
    const int k0 = ks*32;
    if (ks) __syncthreads();
    {
      u8v u = *(const u8v*)(xc + (size_t)(row0+ar)*256 + k0 + ag*8);
      *(u8v*)&Ast[tile_off(ar, ag, 0)] = u;
    }
    {
      s8v hv;
      #pragma unroll
      for (int i=0;i<8;++i) {
        int k = k0 + bg*8 + i;
        float f = (bn < 40) ? Wx[(size_t)k*40 + bn] : 0.f;
        hv[i] = (short)bfr(f);
      }
      *(s8v*)&Bst[tile_off(bn, bg, 0)] = hv;
    }
    __syncthreads();
    const int gsh = ((kg ^ ((r16>>1)&3)) << 3);
    s8v fa[2], fb[2];
    #pragma unroll
    for (int m=0;m<2;++m) fa[m] = *(const s8v*)&Ast[(wr*2+m)*512 + r16*32 + gsh];
    #pragma unroll
    for (int n=0;n<2;++n) fb[n] = *(const s8v*)&Bst[(wc*2+n)*512 + r16*32 + gsh];
    #pragma unroll
    for (int m=0;m<2;++m)
      #pragma unroll
      for (int n=0;n<2;++n)
        acc[m][n] = __builtin_amdgcn_mfma_f32_16x16x32_bf16(fa[m], fb[n], acc[m][n], 0,0,0);
  }
  #pragma unroll
  for (int m=0;m<2;++m)
    #pragma unroll
    for (int n=0;n<2;++n) {
      int col = wc*32 + n*16 + r16;
      if (col < 40) {
        #pragma unroll
        for (int v=0;v<4;++v) {
          int row = row0 + wr*32 + m*16 + kg*4 + v;
          xdb[(size_t)row*40 + col] = acc[m][n][v];
        }
      }
    }
}

// ---------------- pass1: per-chunk local scan; packed-f32 dual chains ----------------
__global__ __launch_bounds__(128,4) void k_pass1(
    const float* __restrict__ xdbf, const float* __restrict__ xdbb,
    const unsigned short* __restrict__ xcf, const unsigned short* __restrict__ xcb,
    const float* __restrict__ Wdtf, const float* __restrict__ Wdtb,
    const float* __restrict__ bdtf, const float* __restrict__ bdtb,
    const float* __restrict__ Alf, const float* __restrict__ Alb,
    float* __restrict__ sdtf, float* __restrict__ sdtb,
    float* __restrict__ hkf, float* __restrict__ hkb)
{
  const int dir = blockIdx.y;
  const float* __restrict__ xdb = dir ? xdbb : xdbf;
  const unsigned short* __restrict__ xc = dir ? xcb : xcf;
  const float* __restrict__ Wdt = dir ? Wdtb : Wdtf;
  const float* __restrict__ bdt = dir ? bdtb : bdtf;
  const float* __restrict__ Al  = dir ? Alb  : Alf;
  float* __restrict__ sdt = dir ? sdtb : sdtf;
  float* __restrict__ hk  = dir ? hkb  : hkf;
  const int dh = blockIdx.x & 1;
  const int cc = blockIdx.x >> 1;
  const int b = cc >> 7, c = cc & 127;
  const int t0 = c * LCn;
  __shared__ float S[LCn*32];
  const int tid = threadIdx.x;
  #pragma unroll
  for (int j=0;j<6;++j) {
    int idx = tid + j*128;
    int t = idx/24, jj = idx - t*24;
    S[t*32 + jj] = xdb[(size_t)(b*Ln + t0 + t)*40 + jj];
  }
  const int d = dh*128 + tid;
  float Areg[16];
  bool st = true;
  #pragma unroll
  for (int s=0;s<16;++s) {
    Areg[s] = -__expf(Al[d*16+s]);
    st = st && (fabsf(Areg[s] + (float)(s+1)) <= 3e-5f*(float)(s+1));
  }
  f2v wdt2[4];
  #pragma unroll
  for (int j=0;j<4;++j) wdt2[j] = (f2v){Wdt[(2*j)*256+d], Wdt[(2*j+1)*256+d]};
  const float bd = bdt[d];
  f2v h2[8];
  #pragma unroll
  for (int i=0;i<8;++i) h2[i] = (f2v){0.f,0.f};
  float sacc = 0.f;
  const unsigned short* xcp = xc + (size_t)(b*Ln + t0)*256 + d;
  __syncthreads();
  if (st) {
    for (int t=0;t<LCn;++t) {
      float4 sA = *(const float4*)&S[t*32];
      float4 sB = *(const float4*)&S[t*32+4];
      f2v r2 = (f2v){sA.x,sA.y}*wdt2[0] + (f2v){sA.z,sA.w}*wdt2[1];
      r2 = (f2v){sB.x,sB.y}*wdt2[2] + r2;
      r2 = (f2v){sB.z,sB.w}*wdt2[3] + r2;
      float rr = bd + r2.x + r2.y;
      float dtv, wv;
      sp_w(rr, dtv, wv);
      float4 b0 = *(const float4*)&S[t*32+8];
      float4 b1 = *(const float4*)&S[t*32+12];
      float4 b2 = *(const float4*)&S[t*32+16];
      float4 b3 = *(const float4*)&S[t*32+20];
      float xv = bf2f(xcp[(size_t)t*256]);
      float u = dtv * xv;
      sacc += dtv;
      float w2s = wv*wv;
      float w4 = w2s*w2s, w8 = w4*w4;
      f2v wstep = (f2v){w2s, w2s};
      f2v wpa = (f2v){wv, w2s};
      f2v wpb = wpa * (f2v){w8, w8};
      f2v u2 = (f2v){u, u};
      h2[0] = h2[0]*wpa + u2*(f2v){b0.x,b0.y}; wpa *= wstep;
      h2[4] = h2[4]*wpb + u2*(f2v){b2.x,b2.y}; wpb *= wstep;
      h2[1] = h2[1]*wpa + u2*(f2v){b0.z,b0.w}; wpa *= wstep;
      h2[5] = h2[5]*wpb + u2*(f2v){b2.z,b2.w}; wpb *= wstep;
      h2[2] = h2[2]*wpa + u2*(f2v){b1.x,b1.y}; wpa *= wstep;
      h2[6] = h2[6]*wpb + u2*(f2v){b3.x,b3.y}; wpb *= wstep;
      h2[3] = h2[3]*wpa + u2*(f2v){b1.z,b1.w};
      h2[7] = h2[7]*wpb + u2*(f2v){b3.z,b3.w};
    }
  } else {
    for (int t=0;t<LCn;++t) {
      float4 sA = *(const float4*)&S[t*32];
      float4 sB = *(const float4*)&S[t*32+4];
      float rr = bd;
      rr = fmaf(sA.x,wdt2[0].x, fmaf(sA.y,wdt2[0].y, fmaf(sA.z,wdt2[1].x, fmaf(sA.w,wdt2[1].y, rr))));
      rr = fmaf(sB.x,wdt2[2].x, fmaf(sB.y,wdt2[2].y, fmaf(sB.z,wdt2[3].x, fmaf(sB.w,wdt2[3].y, rr))));
      float dtv, wv;
      sp_w(rr, dtv, wv);
      float bq[16];
      #pragma unroll
      for (int i=0;i<4;++i) *(float4*)&bq[4*i] = *(const float4*)&S[t*32 + 8 + 4*i];
      float xv = bf2f(xcp[(size_t)t*256]);
      float u = dtv * xv;
      sacc += dtv;
      #pragma unroll
      for (int s=0;s<16;++s) {
        float hv = (s&1) ? h2[s>>1].y : h2[s>>1].x;
        hv = fmaf(hv, __expf(dtv*Areg[s]), u*bq[s]);
        if (s&1) h2[s>>1].y = hv; else h2[s>>1].x = hv;
      }
    }
  }
  sdt[(size_t)(b*NCn + c)*256 + d] = sacc;
  #pragma unroll
  for (int i=0;i<8;++i) {
    hk[(size_t)((b*NCn + c)*16 + 2*i)*256 + d]   = h2[i].x;
    hk[(size_t)((b*NCn + c)*16 + 2*i+1)*256 + d] = h2[i].y;
  }
}

// ---------------- pass2: inter-chunk recurrence, explicit prefetch ----------------
__global__ __launch_bounds__(256) void k_pass2(
    const float* __restrict__ Alf, const float* __restrict__ Alb,
    const float* __restrict__ sdtf, const float* __restrict__ sdtb,
    float* __restrict__ hkf, float* __restrict__ hkb)
{
  const int dir = blockIdx.y;
  const float* __restrict__ Al  = dir ? Alb : Alf;
  const float* __restrict__ sdt = dir ? sdtb : sdtf;
  float* __restrict__ hk = dir ? hkb : hkf;
  int g = blockIdx.x*256 + threadIdx.x;
  int d = g & 255, s = (g >> 8) & 15, b = g >> 12;
  float Ad = -__expf(Al[d*16+s]);
  float h = 0.f;
  float sd_n = sdt[(size_t)(b*NCn)*256 + d];
  size_t hi_n = (size_t)((b*NCn)*16 + s)*256 + d;
  float he_n = hk[hi_n];
  for (int c=0;c<NCn;++c) {
    float sd = sd_n, he = he_n;
    size_t hi = hi_n;
    if (c+1 < NCn) {
      int bc = b*NCn + c + 1;
      sd_n = sdt[(size_t)bc*256 + d];
      hi_n = (size_t)(bc*16 + s)*256 + d;
      he_n = hk[hi_n];
    }
    hk[hi] = h;
    h = fmaf(__expf(Ad*sd), h, he);
  }
}

// ---------------- pass3: replay; packed-f32 dual chains; gate silu(z) -> yg bf16 ----------
__global__ __launch_bounds__(128,4) void k_pass3(
    const float* __restrict__ xdbf, const float* __restrict__ xdbb,
    const unsigned short* __restrict__ xcf, const unsigned short* __restrict__ xcb,
    const float* __restrict__ Wdtf, const float* __restrict__ Wdtb,
    const float* __restrict__ bdtf, const float* __restrict__ bdtb,
    const float* __restrict__ Alf, const float* __restrict__ Alb,
    const float* __restrict__ Dvf, const float* __restrict__ Dvb,
    const float* __restrict__ hkf, const float* __restrict__ hkb,
    const unsigned short* __restrict__ zbf, const unsigned short* __restrict__ zbb,
    unsigned short* __restrict__ ygf, unsigned short* __restrict__ ygb)
{
  const int dir = blockIdx.y;
  const float* __restrict__ xdb = dir ? xdbb : xdbf;
  const unsigned short* __restrict__ xc = dir ? xcb : xcf;
  const float* __restrict__ Wdt = dir ? Wdtb : Wdtf;
  const float* __restrict__ bdt = dir ? bdtb : bdtf;
  const float* __restrict__ Al  = dir ? Alb  : Alf;
  const float* __restrict__ Dv  = dir ? Dvb  : Dvf;
  const float* __restrict__ hk  = dir ? hkb  : hkf;
  const unsigned short* __restrict__ zbd = dir ? zbb : zbf;
  unsigned short* __restrict__ yg = dir ? ygb : ygf;
  const int dh = blockIdx.x & 1;
  const int cc = blockIdx.x >> 1;
  const int b = cc >> 7, c = cc & 127;
  const int t0 = c * LCn;
  __shared__ float S[LCn*48];
  const int tid = threadIdx.x;
  #pragma unroll
  for (int j=0;j<10;++j) {
    int idx = tid + j*128;
    int t = idx/40, jj = idx - t*40;
    S[t*48 + jj] = xdb[(size_t)(b*Ln + t0 + t)*40 + jj];
  }
  const int d = dh*128 + tid;
  float Areg[16];
  bool st = true;
  #pragma unroll
  for (int s=0;s<16;++s) {
    Areg[s] = -__expf(Al[d*16+s]);
    st = st && (fabsf(Areg[s] + (float)(s+1)) <= 3e-5f*(float)(s+1));
  }
  f2v wdt2[4];
  #pragma unroll
  for (int j=0;j<4;++j) wdt2[j] = (f2v){Wdt[(2*j)*256+d], Wdt[(2*j+1)*256+d]};
  const float bd = bdt[d];
  const float Dd = Dv[d];
  f2v h2[8];
  #pragma unroll
  for (int i=0;i<8;++i)
    h2[i] = (f2v){hk[(size_t)((b*NCn + c)*16 + 2*i)*256 + d],
                  hk[(size_t)((b*NCn + c)*16 + 2*i+1)*256 + d]};
  const unsigned short* xcp = xc + (size_t)(b*Ln + t0)*256 + d;
  const unsigned short* zbp = zbd + (size_t)(b*Ln + t0)*256 + d;
  unsigned short* ygp = yg + (size_t)(b*Ln + t0)*256 + d;
  __syncthreads();
  if (st) {
    for (int t=0;t<LCn;++t) {
      float4 sA = *(const float4*)&S[t*48];
      float4 sB = *(const float4*)&S[t*48+4];
      f2v r2 = (f2v){sA.x,sA.y}*wdt2[0] + (f2v){sA.z,sA.w}*wdt2[1];
      r2 = (f2v){sB.x,sB.y}*wdt2[2] + r2;
      r2 = (f2v){sB.z,sB.w}*wdt2[3] + r2;
      float rr = bd + r2.x + r2.y;
      float dtv, wv;
      sp_w(rr, dtv, wv);
      float4 b0 = *(const float4*)&S[t*48+8];
      float4 b1 = *(const float4*)&S[t*48+12];
      float4 b2 = *(const float4*)&S[t*48+16];
      float4 b3 = *(const float4*)&S[t*48+20];
      float4 c0 = *(const float4*)&S[t*48+24];
      float4 c1 = *(const float4*)&S[t*48+28];
      float4 c2 = *(const float4*)&S[t*48+32];
      float4 c3 = *(const float4*)&S[t*48+36];
      float xv = bf2f(xcp[(size_t)t*256]);
      float u = dtv * xv;
      float w2s = wv*wv;
      float w4 = w2s*w2s, w8 = w4*w4;
      f2v wstep = (f2v){w2s, w2s};
      f2v wpa = (f2v){wv, w2s};
      f2v wpb = wpa * (f2v){w8, w8};
      f2v u2 = (f2v){u, u};
      f2v yA = (f2v){0.f,0.f}, yB = (f2v){0.f,0.f};
      h2[0] = h2[0]*wpa + u2*(f2v){b0.x,b0.y}; yA = h2[0]*(f2v){c0.x,c0.y} + yA; wpa *= wstep;
      h2[4] = h2[4]*wpb + u2*(f2v){b2.x,b2.y}; yB = h2[4]*(f2v){c2.x,c2.y} + yB; wpb *= wstep;
      h2[1] = h2[1]*wpa + u2*(f2v){b0.z,b0.w}; yA = h2[1]*(f2v){c0.z,c0.w} + yA; wpa *= wstep;
      h2[5] = h2[5]*wpb + u2*(f2v){b2.z,b2.w}; yB = h2[5]*(f2v){c2.z,c2.w} + yB; wpb *= wstep;
      h2[2] = h2[2]*wpa + u2*(f2v){b1.x,b1.y}; yA = h2[2]*(f2v){c1.x,c1.y} + yA; wpa *= wstep;
      h2[6] = h2[6]*wpb + u2*(f2v){b3.x,b3.y}; yB = h2[6]*(f2v){c3.x,c3.y} + yB; wpb *= wstep;
      h2[3] = h2[3]*wpa + u2*(f2v){b1.z,b1.w}; yA = h2[3]*(f2v){c1.z,c1.w} + yA;
      h2[7] = h2[7]*wpb + u2*(f2v){b3.z,b3.w}; yB = h2[7]*(f2v){c3.z,c3.w} + yB;
      float y = yA.x + yA.y + yB.x + yB.y;
      y = fmaf(Dd, xv, y);
      float zv = bf2f(zbp[(size_t)t*256]);
      ygp[(size_t)t*256] = bfr(y * siluf(zv));
    }
  } else {
    for (int t=0;t<LCn;++t) {
      float4 sA = *(const float4*)&S[t*48];
      float4 sB = *(const float4*)&S[t*48+4];
      float rr = bd;
      rr = fmaf(sA.x,wdt2[0].x, fmaf(sA.y,wdt2[0].y, fmaf(sA.z,wdt2[1].x, fmaf(sA.w,wdt2[1].y, rr))));
      rr = fmaf(sB.x,wdt2[2].x, fmaf(sB.y,wdt2[2].y, fmaf(sB.z,wdt2[3].x, fmaf(sB.w,wdt2[3].y, rr))));
      float dtv, wv;
      sp_w(rr, dtv, wv);
      float bq[16], cq[16];
      #pragma unroll
      for (int i=0;i<4;++i) {
        *(float4*)&bq[4*i] = *(const float4*)&S[t*48 + 8 + 4*i];
        *(float4*)&cq[4*i] = *(const float4*)&S[t*48 + 24 + 4*i];
      }
      float xv = bf2f(xcp[(size_t)t*256]);
      float u = dtv * xv;
      float y = 0.f;
      #pragma unroll
      for (int s=0;s<16;++s) {
        float hv = (s&1) ? h2[s>>1].y : h2[s>>1].x;
        hv = fmaf(hv, __expf(dtv*Areg[s]), u*bq[s]);
        if (s&1) h2[s>>1].y = hv; else h2[s>>1].x = hv;
        y = fmaf(hv, cq[s], y);
      }
      y = fmaf(Dd, xv, y);
      float zv = bf2f(zbp[(size_t)t*256]);
      ygp[(size_t)t*256] = bfr(y * siluf(zv));
    }
  }
}

// ---------------- Gout (bf16 MFMA): ypart[dir*2+khalf] = yg[dir] @ W_out[dir] ----------------
__global__ __launch_bounds__(256) void k_gout(
    const unsigned short* __restrict__ ygf, const unsigned short* __restrict__ ygb,
    const float* __restrict__ Wof, const float* __restrict__ Wob,
    float* __restrict__ yp)
{
  const int row0 = blockIdx.x * 128;
  const int khalf = blockIdx.y;
  const int dir = blockIdx.z;
  const unsigned short* __restrict__ ygd = dir ? ygb : ygf;
  const float* __restrict__ Wod = dir ? Wob : Wof;
  float* __restrict__ ypart = yp + (size_t)(dir*2 + khalf) * ROWS * 128;
  const int b = row0 >> 12;
  const int l0 = row0 & (Ln-1);

  __shared__ __align__(16) char smem[SMEMB];
  short* Ast = (short*)smem;
  short* Bst = (short*)smem + 8*512;
  float* Te  = (float*)smem;

  const int tid = threadIdx.x;
  const int lane = tid & 63;
  const int wid = tid >> 6;
  const int wr = wid >> 1, wc = wid & 1;
  const int r16 = lane & 15, kg = lane >> 4;

  const int ar = tid >> 1, kh = tid & 1;
  const int q = tid & 31, kq = tid >> 5;
  const int kbase = 4*kq;
  const int g_true = kq >> 1;
  const int ghalf = (kq & 1) * 4;

  f4v acc[4][4];
  #pragma unroll
  for (int i=0;i<4;++i)
    #pragma unroll
    for (int j=0;j<4;++j) acc[i][j] = (f4v){0.f,0.f,0.f,0.f};

  for (int ks=0; ks<4; ++ks) {
    const int kk0 = khalf*128 + ks*32;
    if (ks) __syncthreads();
    {
      int rl = l0 + ar;
      size_t srow = (size_t)b*Ln + (dir ? (Ln-1-rl) : rl);
      const unsigned short* s = ygd + srow*256 + kk0 + kh*16;
      u8v u0 = *(const u8v*)(s);
      u8v u1 = *(const u8v*)(s + 8);
      int o0 = tile_off(ar, 2*kh,   0);
      int o1 = tile_off(ar, 2*kh+1, 0);
      *(u8v*)&Ast[o0] = u0;
      *(u8v*)&Ast[o1] = u1;
    }
    {
      float4 vb[4];
      #pragma unroll
      for (int kk=0;kk<4;++kk)
        vb[kk] = *(const float4*)(Wod + (size_t)(kk0+kbase+kk)*128 + 4*q);
      #pragma unroll
      for (int e=0;e<4;++e) {
        int r = 4*q + e;
        int off = tile_off(r, g_true, ghalf);
        s4v hv;
        #pragma unroll
        for (int kk=0;kk<4;++kk) hv[kk] = (short)bfr(((const float*)&vb[kk])[e]);
        *(s4v*)&Bst[off] = hv;
      }
    }
    __syncthreads();
    const int gsh = ((kg ^ ((r16>>1)&3)) << 3);
    s8v fa[4], fb[4];
    #pragma unroll
    for (int m=0;m<4;++m) fa[m] = *(const s8v*)&Ast[(wr*4+m)*512 + r16*32 + gsh];
    #pragma unroll
    for (int n=0;n<4;++n) fb[n] = *(const s8v*)&Bst[(wc*4+n)*512 + r16*32 + gsh];
    #pragma unroll
    for (int m=0;m<4;++m)
      #pragma unroll
      for (int n=0;n<4;++n)
        acc[m][n] = __builtin_amdgcn_mfma_f32_16x16x32_bf16(fa[m], fb[n], acc[m][n], 0,0,0);
  }
  __syncthreads();
  float* Tw = Te + wid*1088;
  #pragma unroll
  for (int m=0;m<4;++m) {
    #pragma unroll
    for (int n=0;n<4;++n)
      #pragma unroll
      for (int v=0;v<4;++v)
        Tw[(kg*4+v)*68 + n*16 + r16] = acc[m][n][v];
    #pragma unroll
    for (int rr=0;rr<4;++rr) {
      int r = rr*4 + (lane>>4);
      int c4 = lane & 15;
      float4 v4 = *(const float4*)&Tw[r*68 + c4*4];
      int row = row0 + wr*64 + m*16 + r;
      *(float4*)(ypart + (size_t)row*128 + wc*64 + c4*4) = v4;
    }
  }
}

// ---------------- GroupNorm stats + partial-sum -> ysum ----------------
__global__ __launch_bounds__(256) void k_gnstat(const float* __restrict__ yp,
    float* __restrict__ ysum, float* __restrict__ part)
{
  const int bg = blockIdx.x >> 4;
  const int blk = blockIdx.x & 15;
  const int b = bg >> 2, g = bg & 3;
  const size_t P = (size_t)ROWS*128;
  float s=0.f, q=0.f;
  #pragma unroll
  for (int i=0;i<8;++i) {
    int e4 = blk*2048 + threadIdx.x + i*256;
    int l = e4 >> 3, c4 = e4 & 7;
    size_t base = (size_t)(b*Ln + l)*128 + g*32 + c4*4;
    float4 v0 = *(const float4*)(yp + base);
    float4 v1 = *(const float4*)(yp + P + base);
    float4 v2 = *(const float4*)(yp + 2*P + base);
    float4 v3 = *(const float4*)(yp + 3*P + base);
    float4 v;
    v.x = v0.x+v1.x+v2.x+v3.x;
    v.y = v0.y+v1.y+v2.y+v3.y;
    v.z = v0.z+v1.z+v2.z+v3.z;
    v.w = v0.w+v1.w+v2.w+v3.w;
    *(float4*)(ysum + base) = v;
    s += v.x+v.y+v.z+v.w;
    q = fmaf(v.x,v.x, fmaf(v.y,v.y, fmaf(v.z,v.z, fmaf(v.w,v.w, q))));
  }
  __shared__ float rs[256], rq[256];
  rs[threadIdx.x]=s; rq[threadIdx.x]=q;
  __syncthreads();
  for (int off=128; off>0; off>>=1) {
    if (threadIdx.x < off) { rs[threadIdx.x]+=rs[threadIdx.x+off]; rq[threadIdx.x]+=rq[threadIdx.x+off]; }
    __syncthreads();
  }
  if (threadIdx.x==0) { part[blockIdx.x*2]=rs[0]; part[blockIdx.x*2+1]=rq[0]; }
}

__global__ void k_gnred(const float* __restrict__ part, float* __restrict__ mr)
{
  int t = threadIdx.x;
  if (t < 16) {
    float s=0.f,q=0.f;
    for (int k=0;k<16;++k){ s+=part[(t*16+k)*2]; q+=part[(t*16+k)*2+1]; }
    const float inv = 1.f/131072.f;
    float mean = s*inv;
    float var = fmaf(-mean, mean, q*inv);
    mr[t*2] = mean;
    mr[t*2+1] = rsqrtf(var + 1e-5f);
  }
}

// ---------------- GN apply + silu + residual ----------------
__global__ __launch_bounds__(256) void k_gnapply(const float* __restrict__ ysum,
    const float* __restrict__ mr, const float* __restrict__ gamma, const float* __restrict__ beta,
    const float* __restrict__ x, float* __restrict__ out)
{
  const int b = blockIdx.x >> 6;
  const int l0 = (blockIdx.x & 63) * 64;
  __shared__ float T[64][132];
  const int tid = threadIdx.x;
  #pragma unroll
  for (int j=0;j<8;++j) {
    int f = tid + j*256;
    int l = f >> 5, c4 = f & 31;
    *(float4*)&T[l][c4*4] = *(const float4*)(ysum + (size_t)(b*Ln + l0 + l)*128 + c4*4);
  }
  __syncthreads();
  #pragma unroll
  for (int j=0;j<8;++j) {
    int f = tid + j*256;
    int c = f >> 4, lv = f & 15;
    int bg = b*4 + (c>>5);
    float mean = mr[bg*2];
    float rstd = mr[bg*2+1];
    float gam = gamma[c], bet = beta[c];
    size_t base = (size_t)(b*Cn + c)*Ln + l0 + lv*4;
    float4 xv = *(const float4*)(x + base);
    float4 r;
    r.x = siluf(fmaf((T[lv*4+0][c]-mean)*rstd, gam, bet)) + xv.x;
    r.y = siluf(fmaf((T[lv*4+1][c]-mean)*rstd, gam, bet)) + xv.y;
    r.z = siluf(fmaf((T[lv*4+2][c]-mean)*rstd, gam, bet)) + xv.z;
    r.w = siluf(fmaf((T[lv*4+3][c]-mean)*rstd, gam, bet)) + xv.w;
    *(float4*)(out + base) = r;
  }
}

extern "C" void kernel_launch(void* const* d_in, const int* in_sizes, int n_in,
                              void* d_out, int out_size, void* d_ws, size_t ws_size,
                              hipStream_t stream) {
  const float* x      = (const float*)d_in[0];
  const float* W_in_f = (const float*)d_in[1];
  const float* cw_f   = (const float*)d_in[2];
  const float* cb_f   = (const float*)d_in[3];
  const float* Wx_f   = (const float*)d_in[4];
  const float* Wdt_f  = (const float*)d_in[5];
  const float* bdt_f  = (const float*)d_in[6];
  const float* Al_f   = (const float*)d_in[7];
  const float* D_f    = (const float*)d_in[8];
  const float* Wo_f   = (const float*)d_in[9];
  const float* W_in_b = (const float*)d_in[10];
  const float* cw_b   = (const float*)d_in[11];
  const float* cb_b   = (const float*)d_in[12];
  const float* Wx_b   = (const float*)d_in[13];
  const float* Wdt_b  = (const float*)d_in[14];
  const float* bdt_b  = (const float*)d_in[15];
  const float* Al_b   = (const float*)d_in[16];
  const float* D_b    = (const float*)d_in[17];
  const float* Wo_b   = (const float*)d_in[18];
  const float* gamma  = (const float*)d_in[19];
  const float* beta   = (const float*)d_in[20];
  float* out = (float*)d_out;

  float* w = (float*)d_ws;
  size_t o = 0;
  float* xp0 = w + o; o += (size_t)ROWS*256;
  float* xp1 = w + o; o += (size_t)ROWS*256;
  unsigned short* xc0 = (unsigned short*)(w + o); o += (size_t)ROWS*128;
  unsigned short* xc1 = (unsigned short*)(w + o); o += (size_t)ROWS*128;
  unsigned short* zb0 = (unsigned short*)(w + o); o += (size_t)ROWS*128;
  unsigned short* zb1 = (unsigned short*)(w + o); o += (size_t)ROWS*128;
  unsigned short* yg0 = (unsigned short*)(w + o); o += (size_t)ROWS*128;
  unsigned short* yg1 = (unsigned short*)(w + o); o += (size_t)ROWS*128;
  float* xdb0 = w + o; o += (size_t)ROWS*40;
  float* xdb1 = w + o; o += (size_t)ROWS*40;
  float* sdt0 = w + o; o += (size_t)Bn*NCn*256;
  float* sdt1 = w + o; o += (size_t)Bn*NCn*256;
  float* hk0  = w + o; o += (size_t)Bn*NCn*16*256;
  float* hk1  = w + o; o += (size_t)Bn*NCn*16*256;
  float* part = w + o; o += 512;
  float* mr   = w + o; o += 32;
  float* yp   = xp0;
  float* ysum = xdb0;
  if (ws_size < o*sizeof(float)) return;

  k_g1<<<dim3(ROWS/128, 4, 2), 256, 0, stream>>>(x, W_in_f, W_in_b, xp0, xp1, zb0, zb1);
  k_conv<<<dim3(1024, 2), 256, 0, stream>>>(xp0, xp1, cw_f, cw_b, cb_f, cb_b, xc0, xc1);
  k_g2<<<dim3(ROWS/64, 1, 2), 256, 0, stream>>>(xc0, xc1, Wx_f, Wx_b, xdb0, xdb1);
  k_pass1<<<dim3(Bn*NCn*2, 2), 128, 0, stream>>>(xdb0, xdb1, xc0, xc1, Wdt_f, Wdt_b,
                                                 bdt_f, bdt_b, Al_f, Al_b, sdt0, sdt1, hk0, hk1);
  k_pass2<<<dim3(64, 2), 256, 0, stream>>>(Al_f, Al_b, sdt0, sdt1, hk0, hk1);
  k_pass3<<<dim3(Bn*NCn*2, 2), 128, 0, stream>>>(xdb0, xdb1, xc0, xc1, Wdt_f, Wdt_b,
                                                 bdt_f, bdt_b, Al_f, Al_b, D_f, D_b,
                                                 hk0, hk1, zb0, zb1, yg0, yg1);
  k_gout<<<dim3(ROWS/128, 2, 2), 256, 0, stream>>>(yg0, yg1, Wo_f, Wo_b, yp);
  k_gnstat<<<dim3(256), 256, 0, stream>>>(yp, ysum, part);
  k_gnred<<<dim3(1), 64, 0, stream>>>(part, mr);
  k_gnapply<<<dim3(256), 256, 0, stream>>>(ysum, mr, gamma, beta, x, out);
}